// Round 5
// baseline (244.059 us; speedup 1.0000x reference)
//
#include <hip/hip_runtime.h>

// GCN: 2x GCNConv(+self-loop sym-norm) + ReLU, global mean pool, linear head.
// N=100000, E=1600000, G=100, D_IN=3, H=128, OUT=10.
//
// R23->R24: the consume loop was the stall all along. R19 (LDS stage, 91us)
// and R23 (shfl, 95us) share one structure: `for (j=0; j<cnt; j++)` with
// RUNTIME trip count -> no unroll -> each edge's broadcast (~30-40cy) is
// serialized against its dependent 20-instr FMA chain (~100cy/edge vs ~10
// of real work; consume is ~12us of VALU issue machine-wide, phase A took
// ~80us). uv is already zero-filled for sub>=cnt and a zero record
// contributes exactly 0 (uw=0), so the loop now runs a COMPILE-TIME 16
// trips with #pragma unroll: 64 independent bpermutes + 320 FMAs per chunk,
// fully interleavable. ~1.5x masked VALU work on a 12us base: cheap.
// Also: #pragma unroll 4 on partition/histconv/build edge loops (196-block
// kernels at 0.77 blocks/CU need per-thread MLP). VGPR headroom is real
// (32 used / 64 cap) -- R22's regression was misdiagnosed as spill.
//
// All kernels static + gcn364_ prefix (cross-.so symbol collisions caused the
// round-1 silent failure). Runtime dtype probe handles bf16/fp32 harness mode.

#define DIN 3
#define H 128
#define OUTF 10
#define NWEIGHT (384 + 128 + 16384 + 128 + 1280 + 10)  // W1,b1,W2,b2,Wl,bl
#define ECH 8192            // edges per slice
#define RGSH 9              // region = 512 nodes
#define RGSIZE 512
#define W2FRAG_N 16384      // 8 tiles * 4 kchunks * 64 lanes * 8 elems

typedef float gcn364_f2 __attribute__((ext_vector_type(2)));
typedef float gcn364_f4 __attribute__((ext_vector_type(4)));
typedef short gcn364_s8 __attribute__((ext_vector_type(8)));

__device__ __forceinline__ float gcn364_bf2f(unsigned short u) {
    return __uint_as_float(((unsigned int)u) << 16);
}
__device__ __forceinline__ unsigned short gcn364_f2bf(float f) {
    unsigned int u = __float_as_uint(f);
    u += 0x7FFFu + ((u >> 16) & 1u);   // round-to-nearest-even
    return (unsigned short)(u >> 16);
}

// per-wave dtype probe over x's first 256 ushorts: 1 -> fp32, 0 -> bf16.
__device__ __forceinline__ int gcn364_probe(const unsigned short* __restrict__ xs16) {
    int lane = threadIdx.x & 63;
    int outl = 0;
    #pragma unroll
    for (int k = 0; k < 4; k++) {
        unsigned short u = xs16[lane * 4 + k];
        int e = (u >> 7) & 0xFF;
        outl += (e < 100 || e > 140) ? 1 : 0;
    }
    #pragma unroll
    for (int d = 1; d < 64; d <<= 1) outl += __shfl_xor(outl, d);
    return (outl > 32) ? 1 : 0;
}

// histconv: blocks < S build the per-slice region histogram (coalesced
// hist[s*RG + r] store); all blocks also convert x -> xf4 / weights -> wf,
// build the W2 B-fragment table (bf16), zero pooled, publish flag.
static __global__ void gcn364_histconv(const void* __restrict__ x,
                                       const void* __restrict__ W1, const void* __restrict__ b1,
                                       const void* __restrict__ W2, const void* __restrict__ b2,
                                       const void* __restrict__ Wl, const void* __restrict__ bl,
                                       int* __restrict__ flag,
                                       float4* __restrict__ xf4, float* __restrict__ wf,
                                       unsigned short* __restrict__ w2frag,
                                       float* __restrict__ pooled,
                                       const int* __restrict__ edst,
                                       int* __restrict__ hist,
                                       int N, int E, int S, int RG, int GH) {
    __shared__ int h[256];
    if (blockIdx.x < (unsigned)S) {
        h[threadIdx.x] = 0;
        __syncthreads();
        int elo = blockIdx.x * ECH;
        int ehi = elo + ECH; if (ehi > E) ehi = E;
        #pragma unroll 4
        for (int e = elo + threadIdx.x; e < ehi; e += 256)
            atomicAdd(&h[edst[e] >> RGSH], 1);
        __syncthreads();
        if (threadIdx.x < RG) hist[blockIdx.x * RG + threadIdx.x] = h[threadIdx.x];
    }
    int i = blockIdx.x * blockDim.x + threadIdx.x;
    if (i < GH) pooled[i] = 0.0f;
    int total = N + NWEIGHT;
    if ((int)blockIdx.x * 256 < total) {
        int fl = gcn364_probe((const unsigned short*)x);
        if (i == 0) *flag = fl;
        if (i < N) {
            float a, b, c;
            if (fl) {
                const float* xs = (const float*)x;
                a = xs[3 * i]; b = xs[3 * i + 1]; c = xs[3 * i + 2];
            } else {
                const unsigned short* xs = (const unsigned short*)x;
                a = gcn364_bf2f(xs[3 * i]);
                b = gcn364_bf2f(xs[3 * i + 1]);
                c = gcn364_bf2f(xs[3 * i + 2]);
            }
            xf4[i] = make_float4(a, b, c, 0.f);
        } else if (i < total) {
            int j = i - N;
            const void* srcp;
            if      (j < 384)                       { srcp = W1; }
            else if ((j -= 384)   < 128)            { srcp = b1; }
            else if ((j -= 128)   < 16384)          { srcp = W2; }
            else if ((j -= 16384) < 128)            { srcp = b2; }
            else if ((j -= 128)   < 1280)           { srcp = Wl; }
            else    { j -= 1280;                      srcp = bl; }
            wf[i - N] = fl ? ((const float*)srcp)[j]
                           : gcn364_bf2f(((const unsigned short*)srcp)[j]);
        }
        // W2 B-fragment table: frag[t][c][lane][j] = bf16(W2[k][n]),
        // k = c*32 + (lane>>4)*8 + j, n = t*16 + (lane&15)
        if (i < W2FRAG_N) {
            int fl2 = fl;
            int j = i & 7;
            int l = (i >> 3) & 63;
            int c = (i >> 9) & 3;
            int t = i >> 11;
            int k = c * 32 + (l >> 4) * 8 + j;
            int n = t * 16 + (l & 15);
            float w = fl2 ? ((const float*)W2)[k * H + n]
                          : gcn364_bf2f(((const unsigned short*)W2)[k * H + n]);
            w2frag[i] = gcn364_f2bf(w);
        }
    }
}

// scanHpar: block r turns hist[s*RG+r] (counts) into the exclusive prefix
// over slices s, in place, and writes the region-r total into regionBase[r].
// Chunked: 256 slices per round, parallel strided loads + LDS scan.
static __global__ void gcn364_scanHpar(int* __restrict__ hist,
                                       int* __restrict__ regionBase,
                                       int S, int RG) {
    __shared__ int sh[256];
    int r = blockIdx.x;
    int t = threadIdx.x;
    int carry = 0;
    for (int s0 = 0; s0 < S; s0 += 256) {
        int s = s0 + t;
        int c = (s < S) ? hist[s * RG + r] : 0;
        sh[t] = c;
        __syncthreads();
        for (int d = 1; d < 256; d <<= 1) {
            int v = (t >= d) ? sh[t - d] : 0;
            __syncthreads();
            sh[t] += v;
            __syncthreads();
        }
        int incl = sh[t];
        if (s < S) hist[s * RG + r] = carry + incl - c;   // exclusive prefix
        int tot = sh[255];
        __syncthreads();   // everyone reads sh[255] before next chunk overwrites
        carry += tot;
    }
    if (t == 0) regionBase[r] = carry;   // region total (scanned by scanR)
}

// scanR (1 block): IN-PLACE exclusive scan of regionBase (region totals ->
// exclusive bases); regionBase[RG] = E. Requires RG <= 256 (RG=196 here).
static __global__ void gcn364_scanR(int* __restrict__ regionBase,
                                    int RG, int E) {
    __shared__ int sh[256];
    int t = threadIdx.x;
    int c = (t < RG) ? regionBase[t] : 0;
    sh[t] = c;
    __syncthreads();
    for (int d = 1; d < 256; d <<= 1) {
        int v = (t >= d) ? sh[t - d] : 0;
        __syncthreads();
        sh[t] += v;
        __syncthreads();
    }
    if (t < RG) regionBase[t] = sh[t] - c;   // exclusive
    if (t == 0) regionBase[RG] = E;
}

// partition: slice s scatters its edges into region-major epack order using
// LDS cursors seeded from hist+regionBase. Plain stores only.
// epack = (dlocal << 17) | src
static __global__ void gcn364_partition(const int* __restrict__ src,
                                        const int* __restrict__ dst,
                                        const int* __restrict__ hist,
                                        const int* __restrict__ regionBase,
                                        int* __restrict__ epack,
                                        int E, int RG) {
    __shared__ int cur[256];
    int s = blockIdx.x;
    if (threadIdx.x < RG)
        cur[threadIdx.x] = hist[s * RG + threadIdx.x] + regionBase[threadIdx.x];
    __syncthreads();
    int elo = s * ECH;
    int ehi = elo + ECH; if (ehi > E) ehi = E;
    #pragma unroll 4
    for (int e = elo + threadIdx.x; e < ehi; e += 256) {
        int d = dst[e];
        int sv = src[e];
        int p = atomicAdd(&cur[d >> RGSH], 1);
        epack[p] = ((d & (RGSIZE - 1)) << 17) | sv;
    }
}

// build: one block per region. LDS deg hist over the region's contiguous
// epack run -> LDS scan -> absolute off[] (inclusive ends) -> LDS-cursor
// esrc placement. Also dinvs + xf4 scaling for the region's nodes.
static __global__ void gcn364_build(const int* __restrict__ epack,
                                    const int* __restrict__ regionBase,
                                    int* __restrict__ off,
                                    int* __restrict__ esrc,
                                    float4* __restrict__ xf4,
                                    int N) {
    __shared__ int sdeg[RGSIZE];
    __shared__ int stmp[256];
    int r = blockIdx.x;
    int nlo = r << RGSH;
    int nn = N - nlo; if (nn > RGSIZE) nn = RGSIZE;
    int e0 = regionBase[r];
    int e1 = regionBase[r + 1];
    int t = threadIdx.x;

    sdeg[t] = 0; sdeg[t + 256] = 0;
    __syncthreads();
    #pragma unroll 4
    for (int p = e0 + t; p < e1; p += 256)
        atomicAdd(&sdeg[epack[p] >> 17], 1);
    __syncthreads();

    int a0 = sdeg[2 * t];
    int a1 = sdeg[2 * t + 1];
    int psum = a0 + a1;
    stmp[t] = psum;
    __syncthreads();
    for (int d = 1; d < 256; d <<= 1) {
        int val = (t >= d) ? stmp[t - d] : 0;
        __syncthreads();
        stmp[t] += val;
        __syncthreads();
    }
    int excl = stmp[t] - psum;

    if (2 * t < nn)     off[nlo + 2 * t]     = e0 + excl + a0;
    if (2 * t + 1 < nn) off[nlo + 2 * t + 1] = e0 + excl + a0 + a1;
    if (2 * t < nn) {
        float di = rsqrtf((float)a0 + 1.0f);
        float4 xv = xf4[nlo + 2 * t];
        xv.x *= di; xv.y *= di; xv.z *= di; xv.w = di;
        xf4[nlo + 2 * t] = xv;
    }
    if (2 * t + 1 < nn) {
        float di = rsqrtf((float)a1 + 1.0f);
        float4 xv = xf4[nlo + 2 * t + 1];
        xv.x *= di; xv.y *= di; xv.z *= di; xv.w = di;
        xf4[nlo + 2 * t + 1] = xv;
    }
    sdeg[2 * t]     = e0 + excl;
    sdeg[2 * t + 1] = e0 + excl + a0;
    __syncthreads();
    #pragma unroll 4
    for (int p = e0 + t; p < e1; p += 256) {
        int v = epack[p];
        int q = atomicAdd(&sdeg[v >> 17], 1);
        esrc[q] = v & 0x1FFFF;
    }
}

// Layer-1 aggregation -> u4 records. 16 lanes per node, 4 nodes per wave.
static __global__ void gcn364_aggu(const int* __restrict__ esrc,
                                   const int* __restrict__ off,
                                   const float4* __restrict__ xf4,
                                   float4* __restrict__ u4, int N) {
    int lane = threadIdx.x & 63;
    int wv = threadIdx.x >> 6;
    int grp = lane >> 4;
    int sub = lane & 15;
    int i = (blockIdx.x * 4 + wv) * 4 + grp;

    float a0 = 0.f, a1 = 0.f, a2 = 0.f;
    if (i < N) {
        int p0 = (i == 0) ? 0 : off[i - 1];
        int p1 = off[i];
        for (int p = p0 + sub; p < p1; p += 16) {
            float4 sv = xf4[esrc[p]];
            a0 += sv.x; a1 += sv.y; a2 += sv.z;
        }
    }
    for (int d = 1; d < 16; d <<= 1) {
        a0 += __shfl_xor(a0, d);
        a1 += __shfl_xor(a1, d);
        a2 += __shfl_xor(a2, d);
    }
    if (i < N && sub == 0) {
        float4 xi = xf4[i];
        float di = xi.w;
        u4[i] = make_float4(di * (a0 + xi.x), di * (a1 + xi.y), di * (a2 + xi.z), di);
    }
}

// per-edge layer-1 row recompute + accumulate (packed dual-fp32)
__device__ __forceinline__ void gcn364_edge(const float4 u,
                                            const gcn364_f2* wa2, const gcn364_f2* wb2,
                                            const gcn364_f2* wc2, const gcn364_f2* bb2,
                                            gcn364_f2* acc) {
    gcn364_f2 ux = {u.x, u.x}, uy = {u.y, u.y}, uz = {u.z, u.z}, uw = {u.w, u.w};
    gcn364_f2 zero = {0.f, 0.f};
    #pragma unroll
    for (int q = 0; q < 4; q++) {
        gcn364_f2 t = ux * wa2[q] + uy * wb2[q] + uz * wc2[q] + bb2[q];
        t = __builtin_elementwise_max(t, zero);
        acc[q] += uw * t;
    }
}

// group-broadcast of a float4 held per-lane: pull lane (grp*16 + j).
__device__ __forceinline__ float4 gcn364_bcast(const float4 v, int sl) {
    return make_float4(__shfl(v.x, sl), __shfl(v.y, sl),
                       __shfl(v.z, sl), __shfl(v.w, sl));
}

// Fused layer-2: phase A = lane-parallel 16-edge-chunk gather; consume by
// in-register group broadcast over a COMPILE-TIME 16-slot loop (uv is
// zero-filled beyond cnt: uw=0 => zero contribution), fully unrolled so the
// 64 bpermutes + 320 FMAs per chunk interleave. V tile -> bf16 LDS in MFMA
// A-frag layout. Phase B = MFMA 16x16x32 bf16 GEMM + relu + mean-pool.
#define MPB 16
static __global__ __launch_bounds__(256, 8) void gcn364_agg2pool(
        const int* __restrict__ esrc, const int* __restrict__ off,
        const float4* __restrict__ u4,
        const float* __restrict__ w1f, const float* __restrict__ b1f,
        const unsigned short* __restrict__ w2frag, const float* __restrict__ b2f,
        const int* __restrict__ batch, float* __restrict__ pooled, int N) {
    __shared__ unsigned short vshb[MPB][H + 8];   // bf16 V tile, A-frag friendly
    int i0 = blockIdx.x * MPB;
    int tid = threadIdx.x;
    int wave = tid >> 6;
    int lane = tid & 63;
    int grp = lane >> 4;
    int sub = lane & 15;
    int node = wave * 4 + grp;
    int i = i0 + node;
    int gbase = lane & 48;   // grp*16: shuffle source base for this group

    gcn364_f2 wa2[4], wb2[4], wc2[4], bb2[4];
    #pragma unroll
    for (int q = 0; q < 4; q++) {
        int f = sub * 8 + q * 2;
        wa2[q] = (gcn364_f2){w1f[f], w1f[f + 1]};
        wb2[q] = (gcn364_f2){w1f[H + f], w1f[H + f + 1]};
        wc2[q] = (gcn364_f2){w1f[2 * H + f], w1f[2 * H + f + 1]};
        bb2[q] = (gcn364_f2){b1f[f], b1f[f + 1]};
    }

    gcn364_f2 acc[4];
    acc[0] = acc[1] = acc[2] = acc[3] = (gcn364_f2){0.f, 0.f};
    float di = 0.f;
    if (i < N) {
        int p0 = (i == 0) ? 0 : off[i - 1];
        int p1 = off[i];
        for (int base = p0; base < p1; base += 16) {
            int cnt = p1 - base; if (cnt > 16) cnt = 16;
            // lane-parallel gather: coalesced esrc read + 16 independent
            // u4 loads in flight per group; zero-fill beyond cnt (uw=0).
            float4 uv = make_float4(0.f, 0.f, 0.f, 0.f);
            if (sub < cnt) uv = u4[esrc[base + sub]];
            // consume: FIXED 16 trips (zero records are no-ops) -> full
            // unroll, independent bpermutes, scheduler-pipelined.
            #pragma unroll
            for (int j = 0; j < 16; j++) {
                float4 u = gcn364_bcast(uv, gbase + j);
                gcn364_edge(u, wa2, wb2, wc2, bb2, acc);
            }
        }
        float4 uS = u4[i];   // self-loop record (load kept AFTER the loop:
        gcn364_edge(uS, wa2, wb2, wc2, bb2, acc);   // hoisting it regressed)
        di = uS.w;
    }
    {   // V row -> bf16 LDS (feats sub*8..sub*8+7)
        gcn364_s8 o;
        o[0] = (short)gcn364_f2bf(acc[0].x * di);
        o[1] = (short)gcn364_f2bf(acc[0].y * di);
        o[2] = (short)gcn364_f2bf(acc[1].x * di);
        o[3] = (short)gcn364_f2bf(acc[1].y * di);
        o[4] = (short)gcn364_f2bf(acc[2].x * di);
        o[5] = (short)gcn364_f2bf(acc[2].y * di);
        o[6] = (short)gcn364_f2bf(acc[3].x * di);
        o[7] = (short)gcn364_f2bf(acc[3].y * di);
        *(gcn364_s8*)&vshb[node][sub * 8] = o;
    }
    __syncthreads();

    // Phase B: MFMA. A[m][k]: m = lane&15 (node), k = quad*8+j over chunks.
    int m = lane & 15;
    int quad = lane >> 4;
    gcn364_s8 af[4];
    #pragma unroll
    for (int c = 0; c < 4; c++)
        af[c] = *(const gcn364_s8*)&vshb[m][c * 32 + quad * 8];

    #pragma unroll
    for (int tt = 0; tt < 2; tt++) {
        int t = wave * 2 + tt;                // n-tile 0..7
        gcn364_f4 cacc = {0.f, 0.f, 0.f, 0.f};
        #pragma unroll
        for (int c = 0; c < 4; c++) {
            gcn364_s8 bf8 = *(const gcn364_s8*)&w2frag[(((t * 4 + c) * 64) + lane) * 8];
            cacc = __builtin_amdgcn_mfma_f32_16x16x32_bf16(af[c], bf8, cacc, 0, 0, 0);
        }
        // C/D: col = lane&15 (feat within tile), row = (lane>>4)*4 + reg (node)
        int feat = t * 16 + (lane & 15);
        float bb = b2f[feat];
        int baseRow = (lane >> 4) * 4;
        float sum = 0.0f;
        int curg = -1;
        #pragma unroll
        for (int r = 0; r < 4; r++) {
            int ii = i0 + baseRow + r;
            if (ii >= N) continue;
            float val = fmaxf(cacc[r] + bb, 0.0f);
            int g = batch[ii];
            if (g != curg) {
                if (curg >= 0) atomicAdd(&pooled[curg * H + feat], sum);
                curg = g;
                sum = 0.0f;
            }
            sum += val;
        }
        if (curg >= 0) atomicAdd(&pooled[curg * H + feat], sum);
    }
}

// out[g] = (pooled[g]/cnt_g) @ Wl + bl  -> detected dtype.
static __global__ void gcn364_final(const float* __restrict__ pooled,
                                    const int* __restrict__ batch,
                                    const float* __restrict__ wlf,
                                    const float* __restrict__ blf,
                                    const int* __restrict__ flag,
                                    void* __restrict__ out, int N, int G) {
    int g = blockIdx.x;
    int o = threadIdx.x;
    if (g >= G || o >= OUTF) return;
    int lo = 0, hi = N;
    while (lo < hi) { int m = (lo + hi) >> 1; if (batch[m] < g) lo = m + 1; else hi = m; }
    int a = lo;
    lo = 0; hi = N;
    while (lo < hi) { int m = (lo + hi) >> 1; if (batch[m] < g + 1) lo = m + 1; else hi = m; }
    float cn = (float)(lo - a);
    float inv = 1.0f / fmaxf(cn, 1.0f);
    float acc = 0.0f;
    for (int k = 0; k < H; k++)
        acc += pooled[g * H + k] * wlf[k * OUTF + o];
    float v = acc * inv + blf[o];
    if (*flag) ((float*)out)[g * OUTF + o] = v;
    else       ((unsigned short*)out)[g * OUTF + o] = gcn364_f2bf(v);
}

extern "C" void kernel_launch(void* const* d_in, const int* in_sizes, int n_in,
                              void* d_out, int out_size, void* d_ws, size_t ws_size,
                              hipStream_t stream) {
    const void* x  = d_in[0];
    const int* edge_index = (const int*)d_in[1];
    const int* batch      = (const int*)d_in[2];
    const void* W1 = d_in[3];
    const void* b1 = d_in[4];
    const void* W2 = d_in[5];
    const void* b2 = d_in[6];
    const void* Wl = d_in[7];
    const void* bl = d_in[8];

    const int N = in_sizes[0] / DIN;
    const int E = in_sizes[1] / 2;
    const int G = out_size / OUTF;
    const int* src = edge_index;
    const int* dst = edge_index + E;
    const int S  = (E + ECH - 1) / ECH;       // edge slices (196)
    const int RG = (N + RGSIZE - 1) >> RGSH;  // node regions (<= 256)
    const int GH = G * H;

    // ---- workspace layout (BYTE-IDENTICAL to the verified R19 layout) ----
    char* wsb = (char*)d_ws;
    float* pooled     = (float*)wsb;                              // G*H
    int*   hist       = (int*)(pooled + (size_t)GH);              // S*RG
    int*   regionBase = hist + (size_t)S * RG;                    // RG+1
    int*   off        = regionBase + RG + 1;                      // N
    int*   flag       = off + N;                                  // 1
    size_t ofs = (((size_t)((char*)(flag + 1) - wsb)) + 15) & ~(size_t)15;
    float4* xf4  = (float4*)(wsb + ofs);                          // N float4
    float4* u4   = xf4 + N;                                       // N float4
    float*  wf   = (float*)(u4 + N);                              // NWEIGHT
    size_t ofs2 = (((size_t)((char*)(wf + NWEIGHT) - wsb)) + 15) & ~(size_t)15;
    unsigned short* w2frag = (unsigned short*)(wsb + ofs2);       // 16384 ushort
    int*    epack = (int*)(w2frag + W2FRAG_N);                    // E
    int*    esrc  = epack + E;                                    // E

    float* w1f = wf;
    float* b1f = w1f + 384;
    float* b2f = b1f + 128 + 16384;
    float* wlf = b2f + 128;
    float* blf = wlf + 1280;

    {
        int convBlocks = (N + NWEIGHT + 255) / 256;
        int gmax = (S > convBlocks) ? S : convBlocks;
        gcn364_histconv<<<gmax, 256, 0, stream>>>(
            x, W1, b1, W2, b2, Wl, bl, flag, xf4, wf, w2frag, pooled,
            dst, hist, N, E, S, RG, GH);
    }
    gcn364_scanHpar<<<RG, 256, 0, stream>>>(hist, regionBase, S, RG);
    gcn364_scanR<<<1, 256, 0, stream>>>(regionBase, RG, E);
    gcn364_partition<<<S, 256, 0, stream>>>(src, dst, hist, regionBase, epack, E, RG);
    gcn364_build<<<RG, 256, 0, stream>>>(epack, regionBase, off, esrc, xf4, N);
    gcn364_aggu<<<(N + 15) / 16, 256, 0, stream>>>(esrc, off, xf4, u4, N);
    gcn364_agg2pool<<<(N + MPB - 1) / MPB, 256, 0, stream>>>(
        esrc, off, u4, w1f, b1f, w2frag, b2f, batch, pooled, N);
    gcn364_final<<<G, 64, 0, stream>>>(pooled, batch, wlf, blf, flag, d_out, N, G);
}

// Round 6
// 237.718 us; speedup vs baseline: 1.0267x; 1.0267x over previous
//
#include <hip/hip_runtime.h>

// GCN: 2x GCNConv(+self-loop sym-norm) + ReLU, global mean pool, linear head.
// N=100000, E=1600000, G=100, D_IN=3, H=128, OUT=10.
//
// R24->R25: bulk-gather restructure of agg2pool phase A. Post-mortem chain:
// R19 (LDS stage+b128 broadcast, runtime loop) 91us; R23 (shfl) 95; R24
// (shfl+fixed-16 unroll, 1.45x masked work) 107 -> consume ILP was NOT the
// limit, and b128 broadcast beats bpermute on LDS-pipe cost (1 op/edge vs
// 4). Remaining ~60us over the ~15us VALU+LDS floor = per-group gather->
// consume serialization (each group's 16-edge gather chain ~500-700cy is
// waited on immediately; 4 groups/wave diverge on chunk counts).
// Fix: the block's 16 nodes own a CONTIGUOUS edge range (region-sorted
// epack/esrc). All 256 threads bulk-gather that range (coalesced esrc,
// scattered u4 16B, linear ds_write_b128, 256 loads in flight, no masking)
// into a 512-record LDS stage; barrier; each group consumes its node's
// slice via same-address ds_read_b128 broadcast with #pragma unroll 4.
// Gather latency paid once per block, fully parallel, decoupled. LDS
// 12.6KB -> still 8 blocks/CU. Chunk loop covers >512-edge blocks (mean
// 256, sigma 16: ~never taken twice). Preprocessing/phase B/layout: R24.
//
// All kernels static + gcn364_ prefix (cross-.so symbol collisions caused the
// round-1 silent failure). Runtime dtype probe handles bf16/fp32 harness mode.

#define DIN 3
#define H 128
#define OUTF 10
#define NWEIGHT (384 + 128 + 16384 + 128 + 1280 + 10)  // W1,b1,W2,b2,Wl,bl
#define ECH 8192            // edges per slice
#define RGSH 9              // region = 512 nodes
#define RGSIZE 512
#define W2FRAG_N 16384      // 8 tiles * 4 kchunks * 64 lanes * 8 elems
#define CHE 512             // bulk-gather stage records (float4)

typedef float gcn364_f2 __attribute__((ext_vector_type(2)));
typedef float gcn364_f4 __attribute__((ext_vector_type(4)));
typedef short gcn364_s8 __attribute__((ext_vector_type(8)));

__device__ __forceinline__ float gcn364_bf2f(unsigned short u) {
    return __uint_as_float(((unsigned int)u) << 16);
}
__device__ __forceinline__ unsigned short gcn364_f2bf(float f) {
    unsigned int u = __float_as_uint(f);
    u += 0x7FFFu + ((u >> 16) & 1u);   // round-to-nearest-even
    return (unsigned short)(u >> 16);
}

// per-wave dtype probe over x's first 256 ushorts: 1 -> fp32, 0 -> bf16.
__device__ __forceinline__ int gcn364_probe(const unsigned short* __restrict__ xs16) {
    int lane = threadIdx.x & 63;
    int outl = 0;
    #pragma unroll
    for (int k = 0; k < 4; k++) {
        unsigned short u = xs16[lane * 4 + k];
        int e = (u >> 7) & 0xFF;
        outl += (e < 100 || e > 140) ? 1 : 0;
    }
    #pragma unroll
    for (int d = 1; d < 64; d <<= 1) outl += __shfl_xor(outl, d);
    return (outl > 32) ? 1 : 0;
}

// histconv: blocks < S build the per-slice region histogram (coalesced
// hist[s*RG + r] store); all blocks also convert x -> xf4 / weights -> wf,
// build the W2 B-fragment table (bf16), zero pooled, publish flag.
static __global__ void gcn364_histconv(const void* __restrict__ x,
                                       const void* __restrict__ W1, const void* __restrict__ b1,
                                       const void* __restrict__ W2, const void* __restrict__ b2,
                                       const void* __restrict__ Wl, const void* __restrict__ bl,
                                       int* __restrict__ flag,
                                       float4* __restrict__ xf4, float* __restrict__ wf,
                                       unsigned short* __restrict__ w2frag,
                                       float* __restrict__ pooled,
                                       const int* __restrict__ edst,
                                       int* __restrict__ hist,
                                       int N, int E, int S, int RG, int GH) {
    __shared__ int h[256];
    if (blockIdx.x < (unsigned)S) {
        h[threadIdx.x] = 0;
        __syncthreads();
        int elo = blockIdx.x * ECH;
        int ehi = elo + ECH; if (ehi > E) ehi = E;
        #pragma unroll 4
        for (int e = elo + threadIdx.x; e < ehi; e += 256)
            atomicAdd(&h[edst[e] >> RGSH], 1);
        __syncthreads();
        if (threadIdx.x < RG) hist[blockIdx.x * RG + threadIdx.x] = h[threadIdx.x];
    }
    int i = blockIdx.x * blockDim.x + threadIdx.x;
    if (i < GH) pooled[i] = 0.0f;
    int total = N + NWEIGHT;
    if ((int)blockIdx.x * 256 < total) {
        int fl = gcn364_probe((const unsigned short*)x);
        if (i == 0) *flag = fl;
        if (i < N) {
            float a, b, c;
            if (fl) {
                const float* xs = (const float*)x;
                a = xs[3 * i]; b = xs[3 * i + 1]; c = xs[3 * i + 2];
            } else {
                const unsigned short* xs = (const unsigned short*)x;
                a = gcn364_bf2f(xs[3 * i]);
                b = gcn364_bf2f(xs[3 * i + 1]);
                c = gcn364_bf2f(xs[3 * i + 2]);
            }
            xf4[i] = make_float4(a, b, c, 0.f);
        } else if (i < total) {
            int j = i - N;
            const void* srcp;
            if      (j < 384)                       { srcp = W1; }
            else if ((j -= 384)   < 128)            { srcp = b1; }
            else if ((j -= 128)   < 16384)          { srcp = W2; }
            else if ((j -= 16384) < 128)            { srcp = b2; }
            else if ((j -= 128)   < 1280)           { srcp = Wl; }
            else    { j -= 1280;                      srcp = bl; }
            wf[i - N] = fl ? ((const float*)srcp)[j]
                           : gcn364_bf2f(((const unsigned short*)srcp)[j]);
        }
        // W2 B-fragment table: frag[t][c][lane][j] = bf16(W2[k][n]),
        // k = c*32 + (lane>>4)*8 + j, n = t*16 + (lane&15)
        if (i < W2FRAG_N) {
            int fl2 = fl;
            int j = i & 7;
            int l = (i >> 3) & 63;
            int c = (i >> 9) & 3;
            int t = i >> 11;
            int k = c * 32 + (l >> 4) * 8 + j;
            int n = t * 16 + (l & 15);
            float w = fl2 ? ((const float*)W2)[k * H + n]
                          : gcn364_bf2f(((const unsigned short*)W2)[k * H + n]);
            w2frag[i] = gcn364_f2bf(w);
        }
    }
}

// scanHpar: block r turns hist[s*RG+r] (counts) into the exclusive prefix
// over slices s, in place, and writes the region-r total into regionBase[r].
// Chunked: 256 slices per round, parallel strided loads + LDS scan.
static __global__ void gcn364_scanHpar(int* __restrict__ hist,
                                       int* __restrict__ regionBase,
                                       int S, int RG) {
    __shared__ int sh[256];
    int r = blockIdx.x;
    int t = threadIdx.x;
    int carry = 0;
    for (int s0 = 0; s0 < S; s0 += 256) {
        int s = s0 + t;
        int c = (s < S) ? hist[s * RG + r] : 0;
        sh[t] = c;
        __syncthreads();
        for (int d = 1; d < 256; d <<= 1) {
            int v = (t >= d) ? sh[t - d] : 0;
            __syncthreads();
            sh[t] += v;
            __syncthreads();
        }
        int incl = sh[t];
        if (s < S) hist[s * RG + r] = carry + incl - c;   // exclusive prefix
        int tot = sh[255];
        __syncthreads();   // everyone reads sh[255] before next chunk overwrites
        carry += tot;
    }
    if (t == 0) regionBase[r] = carry;   // region total (scanned by scanR)
}

// scanR (1 block): IN-PLACE exclusive scan of regionBase (region totals ->
// exclusive bases); regionBase[RG] = E. Requires RG <= 256 (RG=196 here).
static __global__ void gcn364_scanR(int* __restrict__ regionBase,
                                    int RG, int E) {
    __shared__ int sh[256];
    int t = threadIdx.x;
    int c = (t < RG) ? regionBase[t] : 0;
    sh[t] = c;
    __syncthreads();
    for (int d = 1; d < 256; d <<= 1) {
        int v = (t >= d) ? sh[t - d] : 0;
        __syncthreads();
        sh[t] += v;
        __syncthreads();
    }
    if (t < RG) regionBase[t] = sh[t] - c;   // exclusive
    if (t == 0) regionBase[RG] = E;
}

// partition: slice s scatters its edges into region-major epack order using
// LDS cursors seeded from hist+regionBase. Plain stores only.
// epack = (dlocal << 17) | src
static __global__ void gcn364_partition(const int* __restrict__ src,
                                        const int* __restrict__ dst,
                                        const int* __restrict__ hist,
                                        const int* __restrict__ regionBase,
                                        int* __restrict__ epack,
                                        int E, int RG) {
    __shared__ int cur[256];
    int s = blockIdx.x;
    if (threadIdx.x < RG)
        cur[threadIdx.x] = hist[s * RG + threadIdx.x] + regionBase[threadIdx.x];
    __syncthreads();
    int elo = s * ECH;
    int ehi = elo + ECH; if (ehi > E) ehi = E;
    #pragma unroll 4
    for (int e = elo + threadIdx.x; e < ehi; e += 256) {
        int d = dst[e];
        int sv = src[e];
        int p = atomicAdd(&cur[d >> RGSH], 1);
        epack[p] = ((d & (RGSIZE - 1)) << 17) | sv;
    }
}

// build: one block per region. LDS deg hist over the region's contiguous
// epack run -> LDS scan -> absolute off[] (inclusive ends) -> LDS-cursor
// esrc placement. Also dinvs + xf4 scaling for the region's nodes.
static __global__ void gcn364_build(const int* __restrict__ epack,
                                    const int* __restrict__ regionBase,
                                    int* __restrict__ off,
                                    int* __restrict__ esrc,
                                    float4* __restrict__ xf4,
                                    int N) {
    __shared__ int sdeg[RGSIZE];
    __shared__ int stmp[256];
    int r = blockIdx.x;
    int nlo = r << RGSH;
    int nn = N - nlo; if (nn > RGSIZE) nn = RGSIZE;
    int e0 = regionBase[r];
    int e1 = regionBase[r + 1];
    int t = threadIdx.x;

    sdeg[t] = 0; sdeg[t + 256] = 0;
    __syncthreads();
    #pragma unroll 4
    for (int p = e0 + t; p < e1; p += 256)
        atomicAdd(&sdeg[epack[p] >> 17], 1);
    __syncthreads();

    int a0 = sdeg[2 * t];
    int a1 = sdeg[2 * t + 1];
    int psum = a0 + a1;
    stmp[t] = psum;
    __syncthreads();
    for (int d = 1; d < 256; d <<= 1) {
        int val = (t >= d) ? stmp[t - d] : 0;
        __syncthreads();
        stmp[t] += val;
        __syncthreads();
    }
    int excl = stmp[t] - psum;

    if (2 * t < nn)     off[nlo + 2 * t]     = e0 + excl + a0;
    if (2 * t + 1 < nn) off[nlo + 2 * t + 1] = e0 + excl + a0 + a1;
    if (2 * t < nn) {
        float di = rsqrtf((float)a0 + 1.0f);
        float4 xv = xf4[nlo + 2 * t];
        xv.x *= di; xv.y *= di; xv.z *= di; xv.w = di;
        xf4[nlo + 2 * t] = xv;
    }
    if (2 * t + 1 < nn) {
        float di = rsqrtf((float)a1 + 1.0f);
        float4 xv = xf4[nlo + 2 * t + 1];
        xv.x *= di; xv.y *= di; xv.z *= di; xv.w = di;
        xf4[nlo + 2 * t + 1] = xv;
    }
    sdeg[2 * t]     = e0 + excl;
    sdeg[2 * t + 1] = e0 + excl + a0;
    __syncthreads();
    #pragma unroll 4
    for (int p = e0 + t; p < e1; p += 256) {
        int v = epack[p];
        int q = atomicAdd(&sdeg[v >> 17], 1);
        esrc[q] = v & 0x1FFFF;
    }
}

// Layer-1 aggregation -> u4 records. 16 lanes per node, 4 nodes per wave.
static __global__ void gcn364_aggu(const int* __restrict__ esrc,
                                   const int* __restrict__ off,
                                   const float4* __restrict__ xf4,
                                   float4* __restrict__ u4, int N) {
    int lane = threadIdx.x & 63;
    int wv = threadIdx.x >> 6;
    int grp = lane >> 4;
    int sub = lane & 15;
    int i = (blockIdx.x * 4 + wv) * 4 + grp;

    float a0 = 0.f, a1 = 0.f, a2 = 0.f;
    if (i < N) {
        int p0 = (i == 0) ? 0 : off[i - 1];
        int p1 = off[i];
        for (int p = p0 + sub; p < p1; p += 16) {
            float4 sv = xf4[esrc[p]];
            a0 += sv.x; a1 += sv.y; a2 += sv.z;
        }
    }
    for (int d = 1; d < 16; d <<= 1) {
        a0 += __shfl_xor(a0, d);
        a1 += __shfl_xor(a1, d);
        a2 += __shfl_xor(a2, d);
    }
    if (i < N && sub == 0) {
        float4 xi = xf4[i];
        float di = xi.w;
        u4[i] = make_float4(di * (a0 + xi.x), di * (a1 + xi.y), di * (a2 + xi.z), di);
    }
}

// per-edge layer-1 row recompute + accumulate (packed dual-fp32)
__device__ __forceinline__ void gcn364_edge(const float4 u,
                                            const gcn364_f2* wa2, const gcn364_f2* wb2,
                                            const gcn364_f2* wc2, const gcn364_f2* bb2,
                                            gcn364_f2* acc) {
    gcn364_f2 ux = {u.x, u.x}, uy = {u.y, u.y}, uz = {u.z, u.z}, uw = {u.w, u.w};
    gcn364_f2 zero = {0.f, 0.f};
    #pragma unroll
    for (int q = 0; q < 4; q++) {
        gcn364_f2 t = ux * wa2[q] + uy * wb2[q] + uz * wc2[q] + bb2[q];
        t = __builtin_elementwise_max(t, zero);
        acc[q] += uw * t;
    }
}

// Fused layer-2: phase A = block-cooperative BULK gather of the block's
// contiguous edge range into a 512-record LDS stage (coalesced esrc,
// scattered u4, linear ds_write_b128, 256 loads in flight), then per-group
// consume of its node's slice via same-address ds_read_b128 broadcast with
// partial unroll. V tile -> bf16 LDS in MFMA A-frag layout. Phase B = MFMA
// 16x16x32 bf16 GEMM + relu + mean-pool.
#define MPB 16
static __global__ __launch_bounds__(256, 8) void gcn364_agg2pool(
        const int* __restrict__ esrc, const int* __restrict__ off,
        const float4* __restrict__ u4,
        const float* __restrict__ w1f, const float* __restrict__ b1f,
        const unsigned short* __restrict__ w2frag, const float* __restrict__ b2f,
        const int* __restrict__ batch, float* __restrict__ pooled, int N) {
    __shared__ unsigned short vshb[MPB][H + 8];   // bf16 V tile, A-frag friendly
    __shared__ float4 sstage[CHE];                // bulk-gathered u4 records
    __shared__ int soff[MPB + 1];                 // node edge-range ends
    int i0 = blockIdx.x * MPB;
    int tid = threadIdx.x;
    int wave = tid >> 6;
    int lane = tid & 63;
    int grp = lane >> 4;
    int sub = lane & 15;
    int node = wave * 4 + grp;
    int i = i0 + node;

    if (tid <= MPB) {
        int idx = i0 - 1 + tid;
        int cidx = idx < N - 1 ? idx : N - 1;
        soff[tid] = (idx < 0) ? 0 : off[cidx];
    }

    gcn364_f2 wa2[4], wb2[4], wc2[4], bb2[4];
    #pragma unroll
    for (int q = 0; q < 4; q++) {
        int f = sub * 8 + q * 2;
        wa2[q] = (gcn364_f2){w1f[f], w1f[f + 1]};
        wb2[q] = (gcn364_f2){w1f[H + f], w1f[H + f + 1]};
        wc2[q] = (gcn364_f2){w1f[2 * H + f], w1f[2 * H + f + 1]};
        bb2[q] = (gcn364_f2){b1f[f], b1f[f + 1]};
    }
    __syncthreads();

    int s  = soff[node];      // this node's edge range [s, e)
    int e  = soff[node + 1];
    int e0 = soff[0];         // block edge range [e0, e1)
    int e1 = soff[MPB];

    gcn364_f2 acc[4];
    acc[0] = acc[1] = acc[2] = acc[3] = (gcn364_f2){0.f, 0.f};
    for (int cb = e0; cb < e1; cb += CHE) {
        int ce = cb + CHE; if (ce > e1) ce = e1;
        // bulk gather: 256 threads, coalesced esrc, scattered u4 16B reads,
        // linear LDS writes; no masking waste, full MLP.
        for (int p = cb + tid; p < ce; p += 256)
            sstage[p - cb] = u4[esrc[p]];
        __syncthreads();
        // consume: group-uniform slice, same-address b128 broadcast reads,
        // partial unroll for 4 independent read+FMA streams.
        int lo = s > cb ? s : cb;
        int hi = e < ce ? e : ce;
        #pragma unroll 4
        for (int p = lo; p < hi; p++) {
            float4 u = sstage[p - cb];
            gcn364_edge(u, wa2, wb2, wc2, bb2, acc);
        }
        __syncthreads();
    }
    float di = 0.f;
    if (i < N) {
        float4 uS = u4[i];   // self-loop record
        gcn364_edge(uS, wa2, wb2, wc2, bb2, acc);
        di = uS.w;
    }
    {   // V row -> bf16 LDS (feats sub*8..sub*8+7)
        gcn364_s8 o;
        o[0] = (short)gcn364_f2bf(acc[0].x * di);
        o[1] = (short)gcn364_f2bf(acc[0].y * di);
        o[2] = (short)gcn364_f2bf(acc[1].x * di);
        o[3] = (short)gcn364_f2bf(acc[1].y * di);
        o[4] = (short)gcn364_f2bf(acc[2].x * di);
        o[5] = (short)gcn364_f2bf(acc[2].y * di);
        o[6] = (short)gcn364_f2bf(acc[3].x * di);
        o[7] = (short)gcn364_f2bf(acc[3].y * di);
        *(gcn364_s8*)&vshb[node][sub * 8] = o;
    }
    __syncthreads();

    // Phase B: MFMA. A[m][k]: m = lane&15 (node), k = quad*8+j over chunks.
    int m = lane & 15;
    int quad = lane >> 4;
    gcn364_s8 af[4];
    #pragma unroll
    for (int c = 0; c < 4; c++)
        af[c] = *(const gcn364_s8*)&vshb[m][c * 32 + quad * 8];

    #pragma unroll
    for (int tt = 0; tt < 2; tt++) {
        int t = wave * 2 + tt;                // n-tile 0..7
        gcn364_f4 cacc = {0.f, 0.f, 0.f, 0.f};
        #pragma unroll
        for (int c = 0; c < 4; c++) {
            gcn364_s8 bf8 = *(const gcn364_s8*)&w2frag[(((t * 4 + c) * 64) + lane) * 8];
            cacc = __builtin_amdgcn_mfma_f32_16x16x32_bf16(af[c], bf8, cacc, 0, 0, 0);
        }
        // C/D: col = lane&15 (feat within tile), row = (lane>>4)*4 + reg (node)
        int feat = t * 16 + (lane & 15);
        float bb = b2f[feat];
        int baseRow = (lane >> 4) * 4;
        float sum = 0.0f;
        int curg = -1;
        #pragma unroll
        for (int r = 0; r < 4; r++) {
            int ii = i0 + baseRow + r;
            if (ii >= N) continue;
            float val = fmaxf(cacc[r] + bb, 0.0f);
            int g = batch[ii];
            if (g != curg) {
                if (curg >= 0) atomicAdd(&pooled[curg * H + feat], sum);
                curg = g;
                sum = 0.0f;
            }
            sum += val;
        }
        if (curg >= 0) atomicAdd(&pooled[curg * H + feat], sum);
    }
}

// out[g] = (pooled[g]/cnt_g) @ Wl + bl  -> detected dtype.
static __global__ void gcn364_final(const float* __restrict__ pooled,
                                    const int* __restrict__ batch,
                                    const float* __restrict__ wlf,
                                    const float* __restrict__ blf,
                                    const int* __restrict__ flag,
                                    void* __restrict__ out, int N, int G) {
    int g = blockIdx.x;
    int o = threadIdx.x;
    if (g >= G || o >= OUTF) return;
    int lo = 0, hi = N;
    while (lo < hi) { int m = (lo + hi) >> 1; if (batch[m] < g) lo = m + 1; else hi = m; }
    int a = lo;
    lo = 0; hi = N;
    while (lo < hi) { int m = (lo + hi) >> 1; if (batch[m] < g + 1) lo = m + 1; else hi = m; }
    float cn = (float)(lo - a);
    float inv = 1.0f / fmaxf(cn, 1.0f);
    float acc = 0.0f;
    for (int k = 0; k < H; k++)
        acc += pooled[g * H + k] * wlf[k * OUTF + o];
    float v = acc * inv + blf[o];
    if (*flag) ((float*)out)[g * OUTF + o] = v;
    else       ((unsigned short*)out)[g * OUTF + o] = gcn364_f2bf(v);
}

extern "C" void kernel_launch(void* const* d_in, const int* in_sizes, int n_in,
                              void* d_out, int out_size, void* d_ws, size_t ws_size,
                              hipStream_t stream) {
    const void* x  = d_in[0];
    const int* edge_index = (const int*)d_in[1];
    const int* batch      = (const int*)d_in[2];
    const void* W1 = d_in[3];
    const void* b1 = d_in[4];
    const void* W2 = d_in[5];
    const void* b2 = d_in[6];
    const void* Wl = d_in[7];
    const void* bl = d_in[8];

    const int N = in_sizes[0] / DIN;
    const int E = in_sizes[1] / 2;
    const int G = out_size / OUTF;
    const int* src = edge_index;
    const int* dst = edge_index + E;
    const int S  = (E + ECH - 1) / ECH;       // edge slices (196)
    const int RG = (N + RGSIZE - 1) >> RGSH;  // node regions (<= 256)
    const int GH = G * H;

    // ---- workspace layout (BYTE-IDENTICAL to the verified R19 layout) ----
    char* wsb = (char*)d_ws;
    float* pooled     = (float*)wsb;                              // G*H
    int*   hist       = (int*)(pooled + (size_t)GH);              // S*RG
    int*   regionBase = hist + (size_t)S * RG;                    // RG+1
    int*   off        = regionBase + RG + 1;                      // N
    int*   flag       = off + N;                                  // 1
    size_t ofs = (((size_t)((char*)(flag + 1) - wsb)) + 15) & ~(size_t)15;
    float4* xf4  = (float4*)(wsb + ofs);                          // N float4
    float4* u4   = xf4 + N;                                       // N float4
    float*  wf   = (float*)(u4 + N);                              // NWEIGHT
    size_t ofs2 = (((size_t)((char*)(wf + NWEIGHT) - wsb)) + 15) & ~(size_t)15;
    unsigned short* w2frag = (unsigned short*)(wsb + ofs2);       // 16384 ushort
    int*    epack = (int*)(w2frag + W2FRAG_N);                    // E
    int*    esrc  = epack + E;                                    // E

    float* w1f = wf;
    float* b1f = w1f + 384;
    float* b2f = b1f + 128 + 16384;
    float* wlf = b2f + 128;
    float* blf = wlf + 1280;

    {
        int convBlocks = (N + NWEIGHT + 255) / 256;
        int gmax = (S > convBlocks) ? S : convBlocks;
        gcn364_histconv<<<gmax, 256, 0, stream>>>(
            x, W1, b1, W2, b2, Wl, bl, flag, xf4, wf, w2frag, pooled,
            dst, hist, N, E, S, RG, GH);
    }
    gcn364_scanHpar<<<RG, 256, 0, stream>>>(hist, regionBase, S, RG);
    gcn364_scanR<<<1, 256, 0, stream>>>(regionBase, RG, E);
    gcn364_partition<<<S, 256, 0, stream>>>(src, dst, hist, regionBase, epack, E, RG);
    gcn364_build<<<RG, 256, 0, stream>>>(epack, regionBase, off, esrc, xf4, N);
    gcn364_aggu<<<(N + 15) / 16, 256, 0, stream>>>(esrc, off, xf4, u4, N);
    gcn364_agg2pool<<<(N + MPB - 1) / MPB, 256, 0, stream>>>(
        esrc, off, u4, w1f, b1f, w2frag, b2f, batch, pooled, N);
    gcn364_final<<<G, 64, 0, stream>>>(pooled, batch, wlf, blf, flag, d_out, N, G);
}

// Round 7
// 194.613 us; speedup vs baseline: 1.2541x; 1.2215x over previous
//
#include <hip/hip_runtime.h>

// GCN: 2x GCNConv(+self-loop sym-norm) + ReLU, global mean pool, linear head.
// N=100000, E=1600000, G=100, D_IN=3, H=128, OUT=10.
//
// R25->R26: the pooled-atomic wall. Five phase-A structures (per-group LDS
// stage 91us / shfl 95 / shfl+unroll 107 / bulk gather 97.5) all plateau ->
// the invariant cost is phase B's 4.2M device-scope fp32 atomicAdds
// (6250 blk x 4 wv x 2 tt x 64 ln x ~1.3). Counter evidence: WRITE_SIZE
// 39-65MB every round against a 51KB pooled surface -- per-XCD L2s are not
// coherent, so each atomic resolves at the fabric (one ~12-16B transaction
// each: 4.2M x ~14B = ~50MB = measured). ~40-55us of fabric backpressure =
// the plateau, VALUBusy 35% with nothing else busy.
// Fix: block-level pre-reduction. 16 contiguous nodes span <=2 graphs
// (batch sorted): per (wave,tt) each lane splits its 4 rows into g==g0 /
// g!=g0 partial sums; shfl_xor(16/32) reduces across the 4 quads (same
// feat, different nodes); quad0 plain-stores spool[2][128] (each slot,feat
// has exactly one writer -- no LDS atomics); barrier; 256 threads dump
// <=256 global atomics/block, zeros skipped. 4.2M -> ~0.85M atomics (5x).
// Phase A (R25 bulk gather), preprocessing, workspace layout: untouched.
//
// All kernels static + gcn364_ prefix (cross-.so symbol collisions caused the
// round-1 silent failure). Runtime dtype probe handles bf16/fp32 harness mode.

#define DIN 3
#define H 128
#define OUTF 10
#define NWEIGHT (384 + 128 + 16384 + 128 + 1280 + 10)  // W1,b1,W2,b2,Wl,bl
#define ECH 8192            // edges per slice
#define RGSH 9              // region = 512 nodes
#define RGSIZE 512
#define W2FRAG_N 16384      // 8 tiles * 4 kchunks * 64 lanes * 8 elems
#define CHE 512             // bulk-gather stage records (float4)

typedef float gcn364_f2 __attribute__((ext_vector_type(2)));
typedef float gcn364_f4 __attribute__((ext_vector_type(4)));
typedef short gcn364_s8 __attribute__((ext_vector_type(8)));

__device__ __forceinline__ float gcn364_bf2f(unsigned short u) {
    return __uint_as_float(((unsigned int)u) << 16);
}
__device__ __forceinline__ unsigned short gcn364_f2bf(float f) {
    unsigned int u = __float_as_uint(f);
    u += 0x7FFFu + ((u >> 16) & 1u);   // round-to-nearest-even
    return (unsigned short)(u >> 16);
}

// per-wave dtype probe over x's first 256 ushorts: 1 -> fp32, 0 -> bf16.
__device__ __forceinline__ int gcn364_probe(const unsigned short* __restrict__ xs16) {
    int lane = threadIdx.x & 63;
    int outl = 0;
    #pragma unroll
    for (int k = 0; k < 4; k++) {
        unsigned short u = xs16[lane * 4 + k];
        int e = (u >> 7) & 0xFF;
        outl += (e < 100 || e > 140) ? 1 : 0;
    }
    #pragma unroll
    for (int d = 1; d < 64; d <<= 1) outl += __shfl_xor(outl, d);
    return (outl > 32) ? 1 : 0;
}

// histconv: blocks < S build the per-slice region histogram (coalesced
// hist[s*RG + r] store); all blocks also convert x -> xf4 / weights -> wf,
// build the W2 B-fragment table (bf16), zero pooled, publish flag.
static __global__ void gcn364_histconv(const void* __restrict__ x,
                                       const void* __restrict__ W1, const void* __restrict__ b1,
                                       const void* __restrict__ W2, const void* __restrict__ b2,
                                       const void* __restrict__ Wl, const void* __restrict__ bl,
                                       int* __restrict__ flag,
                                       float4* __restrict__ xf4, float* __restrict__ wf,
                                       unsigned short* __restrict__ w2frag,
                                       float* __restrict__ pooled,
                                       const int* __restrict__ edst,
                                       int* __restrict__ hist,
                                       int N, int E, int S, int RG, int GH) {
    __shared__ int h[256];
    if (blockIdx.x < (unsigned)S) {
        h[threadIdx.x] = 0;
        __syncthreads();
        int elo = blockIdx.x * ECH;
        int ehi = elo + ECH; if (ehi > E) ehi = E;
        #pragma unroll 4
        for (int e = elo + threadIdx.x; e < ehi; e += 256)
            atomicAdd(&h[edst[e] >> RGSH], 1);
        __syncthreads();
        if (threadIdx.x < RG) hist[blockIdx.x * RG + threadIdx.x] = h[threadIdx.x];
    }
    int i = blockIdx.x * blockDim.x + threadIdx.x;
    if (i < GH) pooled[i] = 0.0f;
    int total = N + NWEIGHT;
    if ((int)blockIdx.x * 256 < total) {
        int fl = gcn364_probe((const unsigned short*)x);
        if (i == 0) *flag = fl;
        if (i < N) {
            float a, b, c;
            if (fl) {
                const float* xs = (const float*)x;
                a = xs[3 * i]; b = xs[3 * i + 1]; c = xs[3 * i + 2];
            } else {
                const unsigned short* xs = (const unsigned short*)x;
                a = gcn364_bf2f(xs[3 * i]);
                b = gcn364_bf2f(xs[3 * i + 1]);
                c = gcn364_bf2f(xs[3 * i + 2]);
            }
            xf4[i] = make_float4(a, b, c, 0.f);
        } else if (i < total) {
            int j = i - N;
            const void* srcp;
            if      (j < 384)                       { srcp = W1; }
            else if ((j -= 384)   < 128)            { srcp = b1; }
            else if ((j -= 128)   < 16384)          { srcp = W2; }
            else if ((j -= 16384) < 128)            { srcp = b2; }
            else if ((j -= 128)   < 1280)           { srcp = Wl; }
            else    { j -= 1280;                      srcp = bl; }
            wf[i - N] = fl ? ((const float*)srcp)[j]
                           : gcn364_bf2f(((const unsigned short*)srcp)[j]);
        }
        // W2 B-fragment table: frag[t][c][lane][j] = bf16(W2[k][n]),
        // k = c*32 + (lane>>4)*8 + j, n = t*16 + (lane&15)
        if (i < W2FRAG_N) {
            int fl2 = fl;
            int j = i & 7;
            int l = (i >> 3) & 63;
            int c = (i >> 9) & 3;
            int t = i >> 11;
            int k = c * 32 + (l >> 4) * 8 + j;
            int n = t * 16 + (l & 15);
            float w = fl2 ? ((const float*)W2)[k * H + n]
                          : gcn364_bf2f(((const unsigned short*)W2)[k * H + n]);
            w2frag[i] = gcn364_f2bf(w);
        }
    }
}

// scanHpar: block r turns hist[s*RG+r] (counts) into the exclusive prefix
// over slices s, in place, and writes the region-r total into regionBase[r].
// Chunked: 256 slices per round, parallel strided loads + LDS scan.
static __global__ void gcn364_scanHpar(int* __restrict__ hist,
                                       int* __restrict__ regionBase,
                                       int S, int RG) {
    __shared__ int sh[256];
    int r = blockIdx.x;
    int t = threadIdx.x;
    int carry = 0;
    for (int s0 = 0; s0 < S; s0 += 256) {
        int s = s0 + t;
        int c = (s < S) ? hist[s * RG + r] : 0;
        sh[t] = c;
        __syncthreads();
        for (int d = 1; d < 256; d <<= 1) {
            int v = (t >= d) ? sh[t - d] : 0;
            __syncthreads();
            sh[t] += v;
            __syncthreads();
        }
        int incl = sh[t];
        if (s < S) hist[s * RG + r] = carry + incl - c;   // exclusive prefix
        int tot = sh[255];
        __syncthreads();   // everyone reads sh[255] before next chunk overwrites
        carry += tot;
    }
    if (t == 0) regionBase[r] = carry;   // region total (scanned by scanR)
}

// scanR (1 block): IN-PLACE exclusive scan of regionBase (region totals ->
// exclusive bases); regionBase[RG] = E. Requires RG <= 256 (RG=196 here).
static __global__ void gcn364_scanR(int* __restrict__ regionBase,
                                    int RG, int E) {
    __shared__ int sh[256];
    int t = threadIdx.x;
    int c = (t < RG) ? regionBase[t] : 0;
    sh[t] = c;
    __syncthreads();
    for (int d = 1; d < 256; d <<= 1) {
        int v = (t >= d) ? sh[t - d] : 0;
        __syncthreads();
        sh[t] += v;
        __syncthreads();
    }
    if (t < RG) regionBase[t] = sh[t] - c;   // exclusive
    if (t == 0) regionBase[RG] = E;
}

// partition: slice s scatters its edges into region-major epack order using
// LDS cursors seeded from hist+regionBase. Plain stores only.
// epack = (dlocal << 17) | src
static __global__ void gcn364_partition(const int* __restrict__ src,
                                        const int* __restrict__ dst,
                                        const int* __restrict__ hist,
                                        const int* __restrict__ regionBase,
                                        int* __restrict__ epack,
                                        int E, int RG) {
    __shared__ int cur[256];
    int s = blockIdx.x;
    if (threadIdx.x < RG)
        cur[threadIdx.x] = hist[s * RG + threadIdx.x] + regionBase[threadIdx.x];
    __syncthreads();
    int elo = s * ECH;
    int ehi = elo + ECH; if (ehi > E) ehi = E;
    #pragma unroll 4
    for (int e = elo + threadIdx.x; e < ehi; e += 256) {
        int d = dst[e];
        int sv = src[e];
        int p = atomicAdd(&cur[d >> RGSH], 1);
        epack[p] = ((d & (RGSIZE - 1)) << 17) | sv;
    }
}

// build: one block per region. LDS deg hist over the region's contiguous
// epack run -> LDS scan -> absolute off[] (inclusive ends) -> LDS-cursor
// esrc placement. Also dinvs + xf4 scaling for the region's nodes.
static __global__ void gcn364_build(const int* __restrict__ epack,
                                    const int* __restrict__ regionBase,
                                    int* __restrict__ off,
                                    int* __restrict__ esrc,
                                    float4* __restrict__ xf4,
                                    int N) {
    __shared__ int sdeg[RGSIZE];
    __shared__ int stmp[256];
    int r = blockIdx.x;
    int nlo = r << RGSH;
    int nn = N - nlo; if (nn > RGSIZE) nn = RGSIZE;
    int e0 = regionBase[r];
    int e1 = regionBase[r + 1];
    int t = threadIdx.x;

    sdeg[t] = 0; sdeg[t + 256] = 0;
    __syncthreads();
    #pragma unroll 4
    for (int p = e0 + t; p < e1; p += 256)
        atomicAdd(&sdeg[epack[p] >> 17], 1);
    __syncthreads();

    int a0 = sdeg[2 * t];
    int a1 = sdeg[2 * t + 1];
    int psum = a0 + a1;
    stmp[t] = psum;
    __syncthreads();
    for (int d = 1; d < 256; d <<= 1) {
        int val = (t >= d) ? stmp[t - d] : 0;
        __syncthreads();
        stmp[t] += val;
        __syncthreads();
    }
    int excl = stmp[t] - psum;

    if (2 * t < nn)     off[nlo + 2 * t]     = e0 + excl + a0;
    if (2 * t + 1 < nn) off[nlo + 2 * t + 1] = e0 + excl + a0 + a1;
    if (2 * t < nn) {
        float di = rsqrtf((float)a0 + 1.0f);
        float4 xv = xf4[nlo + 2 * t];
        xv.x *= di; xv.y *= di; xv.z *= di; xv.w = di;
        xf4[nlo + 2 * t] = xv;
    }
    if (2 * t + 1 < nn) {
        float di = rsqrtf((float)a1 + 1.0f);
        float4 xv = xf4[nlo + 2 * t + 1];
        xv.x *= di; xv.y *= di; xv.z *= di; xv.w = di;
        xf4[nlo + 2 * t + 1] = xv;
    }
    sdeg[2 * t]     = e0 + excl;
    sdeg[2 * t + 1] = e0 + excl + a0;
    __syncthreads();
    #pragma unroll 4
    for (int p = e0 + t; p < e1; p += 256) {
        int v = epack[p];
        int q = atomicAdd(&sdeg[v >> 17], 1);
        esrc[q] = v & 0x1FFFF;
    }
}

// Layer-1 aggregation -> u4 records. 16 lanes per node, 4 nodes per wave.
static __global__ void gcn364_aggu(const int* __restrict__ esrc,
                                   const int* __restrict__ off,
                                   const float4* __restrict__ xf4,
                                   float4* __restrict__ u4, int N) {
    int lane = threadIdx.x & 63;
    int wv = threadIdx.x >> 6;
    int grp = lane >> 4;
    int sub = lane & 15;
    int i = (blockIdx.x * 4 + wv) * 4 + grp;

    float a0 = 0.f, a1 = 0.f, a2 = 0.f;
    if (i < N) {
        int p0 = (i == 0) ? 0 : off[i - 1];
        int p1 = off[i];
        for (int p = p0 + sub; p < p1; p += 16) {
            float4 sv = xf4[esrc[p]];
            a0 += sv.x; a1 += sv.y; a2 += sv.z;
        }
    }
    for (int d = 1; d < 16; d <<= 1) {
        a0 += __shfl_xor(a0, d);
        a1 += __shfl_xor(a1, d);
        a2 += __shfl_xor(a2, d);
    }
    if (i < N && sub == 0) {
        float4 xi = xf4[i];
        float di = xi.w;
        u4[i] = make_float4(di * (a0 + xi.x), di * (a1 + xi.y), di * (a2 + xi.z), di);
    }
}

// per-edge layer-1 row recompute + accumulate (packed dual-fp32)
__device__ __forceinline__ void gcn364_edge(const float4 u,
                                            const gcn364_f2* wa2, const gcn364_f2* wb2,
                                            const gcn364_f2* wc2, const gcn364_f2* bb2,
                                            gcn364_f2* acc) {
    gcn364_f2 ux = {u.x, u.x}, uy = {u.y, u.y}, uz = {u.z, u.z}, uw = {u.w, u.w};
    gcn364_f2 zero = {0.f, 0.f};
    #pragma unroll
    for (int q = 0; q < 4; q++) {
        gcn364_f2 t = ux * wa2[q] + uy * wb2[q] + uz * wc2[q] + bb2[q];
        t = __builtin_elementwise_max(t, zero);
        acc[q] += uw * t;
    }
}

// Fused layer-2: phase A = block-cooperative bulk gather (R25) + per-edge
// layer-1 recompute; V tile -> bf16 LDS in MFMA A-frag layout. Phase B =
// MFMA 16x16x32 bf16 GEMM + relu, then BLOCK-LEVEL pool reduction: per
// (wave,tt) lanes split their 4 rows into g==g0 / g!=g0 sums (block spans
// <=2 graphs: batch sorted, ~1000 nodes/graph), shfl_xor(16/32) reduces
// across quads, quad0 plain-stores spool[2][128]; barrier; <=256 global
// atomics per block (zeros skipped). 4.2M -> ~0.85M device atomics.
#define MPB 16
static __global__ __launch_bounds__(256, 8) void gcn364_agg2pool(
        const int* __restrict__ esrc, const int* __restrict__ off,
        const float4* __restrict__ u4,
        const float* __restrict__ w1f, const float* __restrict__ b1f,
        const unsigned short* __restrict__ w2frag, const float* __restrict__ b2f,
        const int* __restrict__ batch, float* __restrict__ pooled, int N) {
    __shared__ unsigned short vshb[MPB][H + 8];   // bf16 V tile, A-frag friendly
    __shared__ float4 sstage[CHE];                // bulk-gathered u4 records
    __shared__ int soff[MPB + 1];                 // node edge-range ends
    __shared__ float spool[2][H];                 // per-block pool partials
    int i0 = blockIdx.x * MPB;
    int tid = threadIdx.x;
    int wave = tid >> 6;
    int lane = tid & 63;
    int grp = lane >> 4;
    int sub = lane & 15;
    int node = wave * 4 + grp;
    int i = i0 + node;

    if (tid <= MPB) {
        int idx = i0 - 1 + tid;
        int cidx = idx < N - 1 ? idx : N - 1;
        soff[tid] = (idx < 0) ? 0 : off[cidx];
    }

    gcn364_f2 wa2[4], wb2[4], wc2[4], bb2[4];
    #pragma unroll
    for (int q = 0; q < 4; q++) {
        int f = sub * 8 + q * 2;
        wa2[q] = (gcn364_f2){w1f[f], w1f[f + 1]};
        wb2[q] = (gcn364_f2){w1f[H + f], w1f[H + f + 1]};
        wc2[q] = (gcn364_f2){w1f[2 * H + f], w1f[2 * H + f + 1]};
        bb2[q] = (gcn364_f2){b1f[f], b1f[f + 1]};
    }
    __syncthreads();

    int s  = soff[node];      // this node's edge range [s, e)
    int e  = soff[node + 1];
    int e0 = soff[0];         // block edge range [e0, e1)
    int e1 = soff[MPB];

    gcn364_f2 acc[4];
    acc[0] = acc[1] = acc[2] = acc[3] = (gcn364_f2){0.f, 0.f};
    for (int cb = e0; cb < e1; cb += CHE) {
        int ce = cb + CHE; if (ce > e1) ce = e1;
        // bulk gather: 256 threads, coalesced esrc, scattered u4 16B reads,
        // linear LDS writes; no masking waste, full MLP.
        for (int p = cb + tid; p < ce; p += 256)
            sstage[p - cb] = u4[esrc[p]];
        __syncthreads();
        // consume: group-uniform slice, same-address b128 broadcast reads.
        int lo = s > cb ? s : cb;
        int hi = e < ce ? e : ce;
        #pragma unroll 4
        for (int p = lo; p < hi; p++) {
            float4 u = sstage[p - cb];
            gcn364_edge(u, wa2, wb2, wc2, bb2, acc);
        }
        __syncthreads();
    }
    float di = 0.f;
    if (i < N) {
        float4 uS = u4[i];   // self-loop record
        gcn364_edge(uS, wa2, wb2, wc2, bb2, acc);
        di = uS.w;
    }
    {   // V row -> bf16 LDS (feats sub*8..sub*8+7)
        gcn364_s8 o;
        o[0] = (short)gcn364_f2bf(acc[0].x * di);
        o[1] = (short)gcn364_f2bf(acc[0].y * di);
        o[2] = (short)gcn364_f2bf(acc[1].x * di);
        o[3] = (short)gcn364_f2bf(acc[1].y * di);
        o[4] = (short)gcn364_f2bf(acc[2].x * di);
        o[5] = (short)gcn364_f2bf(acc[2].y * di);
        o[6] = (short)gcn364_f2bf(acc[3].x * di);
        o[7] = (short)gcn364_f2bf(acc[3].y * di);
        *(gcn364_s8*)&vshb[node][sub * 8] = o;
    }
    __syncthreads();

    // Phase B: MFMA. A[m][k]: m = lane&15 (node), k = quad*8+j over chunks.
    int m = lane & 15;
    int quad = lane >> 4;
    int g0 = batch[i0];       // block's first graph (block spans <= 2)
    gcn364_s8 af[4];
    #pragma unroll
    for (int c = 0; c < 4; c++)
        af[c] = *(const gcn364_s8*)&vshb[m][c * 32 + quad * 8];

    #pragma unroll
    for (int tt = 0; tt < 2; tt++) {
        int t = wave * 2 + tt;                // n-tile 0..7
        gcn364_f4 cacc = {0.f, 0.f, 0.f, 0.f};
        #pragma unroll
        for (int c = 0; c < 4; c++) {
            gcn364_s8 bf8 = *(const gcn364_s8*)&w2frag[(((t * 4 + c) * 64) + lane) * 8];
            cacc = __builtin_amdgcn_mfma_f32_16x16x32_bf16(af[c], bf8, cacc, 0, 0, 0);
        }
        // C/D: col = lane&15 (feat within tile), row = (lane>>4)*4 + reg (node)
        int feat = t * 16 + m;
        float bb = b2f[feat];
        int baseRow = quad * 4;
        float sum0 = 0.0f, sum1 = 0.0f;   // g==g0 / g!=g0 partial sums
        #pragma unroll
        for (int r = 0; r < 4; r++) {
            int ii = i0 + baseRow + r;
            if (ii >= N) continue;
            float val = fmaxf(cacc[r] + bb, 0.0f);
            if (batch[ii] == g0) sum0 += val; else sum1 += val;
        }
        // reduce across the 4 quads (same feat, different nodes)
        sum0 += __shfl_xor(sum0, 16); sum0 += __shfl_xor(sum0, 32);
        sum1 += __shfl_xor(sum1, 16); sum1 += __shfl_xor(sum1, 32);
        if (quad == 0) {                   // single writer per (slot,feat)
            spool[0][feat] = sum0;
            spool[1][feat] = sum1;
        }
    }
    __syncthreads();
    // dump: <=256 global atomics per block, zeros skipped.
    {
        int slot = tid >> 7;
        int f = tid & (H - 1);
        float v = spool[slot][f];
        if (v != 0.0f) {
            int il = i0 + MPB - 1; if (il > N - 1) il = N - 1;
            int g = slot ? batch[il] : g0;
            atomicAdd(&pooled[g * H + f], v);
        }
    }
}

// out[g] = (pooled[g]/cnt_g) @ Wl + bl  -> detected dtype.
static __global__ void gcn364_final(const float* __restrict__ pooled,
                                    const int* __restrict__ batch,
                                    const float* __restrict__ wlf,
                                    const float* __restrict__ blf,
                                    const int* __restrict__ flag,
                                    void* __restrict__ out, int N, int G) {
    int g = blockIdx.x;
    int o = threadIdx.x;
    if (g >= G || o >= OUTF) return;
    int lo = 0, hi = N;
    while (lo < hi) { int m = (lo + hi) >> 1; if (batch[m] < g) lo = m + 1; else hi = m; }
    int a = lo;
    lo = 0; hi = N;
    while (lo < hi) { int m = (lo + hi) >> 1; if (batch[m] < g + 1) lo = m + 1; else hi = m; }
    float cn = (float)(lo - a);
    float inv = 1.0f / fmaxf(cn, 1.0f);
    float acc = 0.0f;
    for (int k = 0; k < H; k++)
        acc += pooled[g * H + k] * wlf[k * OUTF + o];
    float v = acc * inv + blf[o];
    if (*flag) ((float*)out)[g * OUTF + o] = v;
    else       ((unsigned short*)out)[g * OUTF + o] = gcn364_f2bf(v);
}

extern "C" void kernel_launch(void* const* d_in, const int* in_sizes, int n_in,
                              void* d_out, int out_size, void* d_ws, size_t ws_size,
                              hipStream_t stream) {
    const void* x  = d_in[0];
    const int* edge_index = (const int*)d_in[1];
    const int* batch      = (const int*)d_in[2];
    const void* W1 = d_in[3];
    const void* b1 = d_in[4];
    const void* W2 = d_in[5];
    const void* b2 = d_in[6];
    const void* Wl = d_in[7];
    const void* bl = d_in[8];

    const int N = in_sizes[0] / DIN;
    const int E = in_sizes[1] / 2;
    const int G = out_size / OUTF;
    const int* src = edge_index;
    const int* dst = edge_index + E;
    const int S  = (E + ECH - 1) / ECH;       // edge slices (196)
    const int RG = (N + RGSIZE - 1) >> RGSH;  // node regions (<= 256)
    const int GH = G * H;

    // ---- workspace layout (BYTE-IDENTICAL to the verified R19 layout) ----
    char* wsb = (char*)d_ws;
    float* pooled     = (float*)wsb;                              // G*H
    int*   hist       = (int*)(pooled + (size_t)GH);              // S*RG
    int*   regionBase = hist + (size_t)S * RG;                    // RG+1
    int*   off        = regionBase + RG + 1;                      // N
    int*   flag       = off + N;                                  // 1
    size_t ofs = (((size_t)((char*)(flag + 1) - wsb)) + 15) & ~(size_t)15;
    float4* xf4  = (float4*)(wsb + ofs);                          // N float4
    float4* u4   = xf4 + N;                                       // N float4
    float*  wf   = (float*)(u4 + N);                              // NWEIGHT
    size_t ofs2 = (((size_t)((char*)(wf + NWEIGHT) - wsb)) + 15) & ~(size_t)15;
    unsigned short* w2frag = (unsigned short*)(wsb + ofs2);       // 16384 ushort
    int*    epack = (int*)(w2frag + W2FRAG_N);                    // E
    int*    esrc  = epack + E;                                    // E

    float* w1f = wf;
    float* b1f = w1f + 384;
    float* b2f = b1f + 128 + 16384;
    float* wlf = b2f + 128;
    float* blf = wlf + 1280;

    {
        int convBlocks = (N + NWEIGHT + 255) / 256;
        int gmax = (S > convBlocks) ? S : convBlocks;
        gcn364_histconv<<<gmax, 256, 0, stream>>>(
            x, W1, b1, W2, b2, Wl, bl, flag, xf4, wf, w2frag, pooled,
            dst, hist, N, E, S, RG, GH);
    }
    gcn364_scanHpar<<<RG, 256, 0, stream>>>(hist, regionBase, S, RG);
    gcn364_scanR<<<1, 256, 0, stream>>>(regionBase, RG, E);
    gcn364_partition<<<S, 256, 0, stream>>>(src, dst, hist, regionBase, epack, E, RG);
    gcn364_build<<<RG, 256, 0, stream>>>(epack, regionBase, off, esrc, xf4, N);
    gcn364_aggu<<<(N + 15) / 16, 256, 0, stream>>>(esrc, off, xf4, u4, N);
    gcn364_agg2pool<<<(N + MPB - 1) / MPB, 256, 0, stream>>>(
        esrc, off, u4, w1f, b1f, w2frag, b2f, batch, pooled, N);
    gcn364_final<<<G, 64, 0, stream>>>(pooled, batch, wlf, blf, flag, d_out, N, G);
}

// Round 8
// 193.268 us; speedup vs baseline: 1.2628x; 1.0070x over previous
//
#include <hip/hip_runtime.h>

// GCN: 2x GCNConv(+self-loop sym-norm) + ReLU, global mean pool, linear head.
// N=100000, E=1600000, G=100, D_IN=3, H=128, OUT=10.
//
// R26->R27: pipeline occupancy. After R26's atomic fix (agg2pool 97.5->56.6us,
// VALUBusy 64%) the pipeline outside agg2pool is 138/194.6us. partition +
// histconv-hist run S=196 blocks = 0.77 blocks/CU -- latency-exposed chains.
// ECH 8192->2048 (S=782, ~3 blocks/CU) with ZERO workspace growth: the
// enlarged hist matrix (782x196 ints = 613KB) ALIASES the esrc slot --
// written by histconv, consumed by scanHpar/partition, dead before build
// writes esrc over it (strict cross-kernel ordering). All other buffers
// keep byte-exact verified offsets (legacy 196-slice hist slot reserved,
// unused). scanHpar now runs 4 chunks (S=782). R20's ECH=2048 attempt grew
// the footprint and died; this one cannot overflow.
// agg2pool (bulk gather + block-level pool reduction): R26-exact.
//
// All kernels static + gcn364_ prefix (cross-.so symbol collisions caused the
// round-1 silent failure). Runtime dtype probe handles bf16/fp32 harness mode.

#define DIN 3
#define H 128
#define OUTF 10
#define NWEIGHT (384 + 128 + 16384 + 128 + 1280 + 10)  // W1,b1,W2,b2,Wl,bl
#define ECH 2048            // edges per slice (hist aliases esrc slot)
#define RGSH 9              // region = 512 nodes
#define RGSIZE 512
#define W2FRAG_N 16384      // 8 tiles * 4 kchunks * 64 lanes * 8 elems
#define CHE 512             // bulk-gather stage records (float4)

typedef float gcn364_f2 __attribute__((ext_vector_type(2)));
typedef float gcn364_f4 __attribute__((ext_vector_type(4)));
typedef short gcn364_s8 __attribute__((ext_vector_type(8)));

__device__ __forceinline__ float gcn364_bf2f(unsigned short u) {
    return __uint_as_float(((unsigned int)u) << 16);
}
__device__ __forceinline__ unsigned short gcn364_f2bf(float f) {
    unsigned int u = __float_as_uint(f);
    u += 0x7FFFu + ((u >> 16) & 1u);   // round-to-nearest-even
    return (unsigned short)(u >> 16);
}

// per-wave dtype probe over x's first 256 ushorts: 1 -> fp32, 0 -> bf16.
__device__ __forceinline__ int gcn364_probe(const unsigned short* __restrict__ xs16) {
    int lane = threadIdx.x & 63;
    int outl = 0;
    #pragma unroll
    for (int k = 0; k < 4; k++) {
        unsigned short u = xs16[lane * 4 + k];
        int e = (u >> 7) & 0xFF;
        outl += (e < 100 || e > 140) ? 1 : 0;
    }
    #pragma unroll
    for (int d = 1; d < 64; d <<= 1) outl += __shfl_xor(outl, d);
    return (outl > 32) ? 1 : 0;
}

// histconv: blocks < S build the per-slice region histogram (coalesced
// hist[s*RG + r] store); blocks < convBlocks also convert x -> xf4 /
// weights -> wf, build the W2 B-fragment table (bf16), zero pooled, publish
// flag. hist lives in the (currently dead) esrc slot.
static __global__ void gcn364_histconv(const void* __restrict__ x,
                                       const void* __restrict__ W1, const void* __restrict__ b1,
                                       const void* __restrict__ W2, const void* __restrict__ b2,
                                       const void* __restrict__ Wl, const void* __restrict__ bl,
                                       int* __restrict__ flag,
                                       float4* __restrict__ xf4, float* __restrict__ wf,
                                       unsigned short* __restrict__ w2frag,
                                       float* __restrict__ pooled,
                                       const int* __restrict__ edst,
                                       int* __restrict__ hist,
                                       int N, int E, int S, int RG, int GH) {
    __shared__ int h[256];
    if (blockIdx.x < (unsigned)S) {
        h[threadIdx.x] = 0;
        __syncthreads();
        int elo = blockIdx.x * ECH;
        int ehi = elo + ECH; if (ehi > E) ehi = E;
        #pragma unroll 4
        for (int e = elo + threadIdx.x; e < ehi; e += 256)
            atomicAdd(&h[edst[e] >> RGSH], 1);
        __syncthreads();
        if (threadIdx.x < RG) hist[blockIdx.x * RG + threadIdx.x] = h[threadIdx.x];
    }
    int i = blockIdx.x * blockDim.x + threadIdx.x;
    if (i < GH) pooled[i] = 0.0f;
    int total = N + NWEIGHT;
    if ((int)blockIdx.x * 256 < total) {
        int fl = gcn364_probe((const unsigned short*)x);
        if (i == 0) *flag = fl;
        if (i < N) {
            float a, b, c;
            if (fl) {
                const float* xs = (const float*)x;
                a = xs[3 * i]; b = xs[3 * i + 1]; c = xs[3 * i + 2];
            } else {
                const unsigned short* xs = (const unsigned short*)x;
                a = gcn364_bf2f(xs[3 * i]);
                b = gcn364_bf2f(xs[3 * i + 1]);
                c = gcn364_bf2f(xs[3 * i + 2]);
            }
            xf4[i] = make_float4(a, b, c, 0.f);
        } else if (i < total) {
            int j = i - N;
            const void* srcp;
            if      (j < 384)                       { srcp = W1; }
            else if ((j -= 384)   < 128)            { srcp = b1; }
            else if ((j -= 128)   < 16384)          { srcp = W2; }
            else if ((j -= 16384) < 128)            { srcp = b2; }
            else if ((j -= 128)   < 1280)           { srcp = Wl; }
            else    { j -= 1280;                      srcp = bl; }
            wf[i - N] = fl ? ((const float*)srcp)[j]
                           : gcn364_bf2f(((const unsigned short*)srcp)[j]);
        }
        // W2 B-fragment table: frag[t][c][lane][j] = bf16(W2[k][n]),
        // k = c*32 + (lane>>4)*8 + j, n = t*16 + (lane&15)
        if (i < W2FRAG_N) {
            int fl2 = fl;
            int j = i & 7;
            int l = (i >> 3) & 63;
            int c = (i >> 9) & 3;
            int t = i >> 11;
            int k = c * 32 + (l >> 4) * 8 + j;
            int n = t * 16 + (l & 15);
            float w = fl2 ? ((const float*)W2)[k * H + n]
                          : gcn364_bf2f(((const unsigned short*)W2)[k * H + n]);
            w2frag[i] = gcn364_f2bf(w);
        }
    }
}

// scanHpar: block r turns hist[s*RG+r] (counts) into the exclusive prefix
// over slices s, in place, and writes the region-r total into regionBase[r].
// Chunked: 256 slices per round (S=782 -> 4 chunks), parallel strided loads
// + LDS scan.
static __global__ void gcn364_scanHpar(int* __restrict__ hist,
                                       int* __restrict__ regionBase,
                                       int S, int RG) {
    __shared__ int sh[256];
    int r = blockIdx.x;
    int t = threadIdx.x;
    int carry = 0;
    for (int s0 = 0; s0 < S; s0 += 256) {
        int s = s0 + t;
        int c = (s < S) ? hist[s * RG + r] : 0;
        sh[t] = c;
        __syncthreads();
        for (int d = 1; d < 256; d <<= 1) {
            int v = (t >= d) ? sh[t - d] : 0;
            __syncthreads();
            sh[t] += v;
            __syncthreads();
        }
        int incl = sh[t];
        if (s < S) hist[s * RG + r] = carry + incl - c;   // exclusive prefix
        int tot = sh[255];
        __syncthreads();   // everyone reads sh[255] before next chunk overwrites
        carry += tot;
    }
    if (t == 0) regionBase[r] = carry;   // region total (scanned by scanR)
}

// scanR (1 block): IN-PLACE exclusive scan of regionBase (region totals ->
// exclusive bases); regionBase[RG] = E. Requires RG <= 256 (RG=196 here).
static __global__ void gcn364_scanR(int* __restrict__ regionBase,
                                    int RG, int E) {
    __shared__ int sh[256];
    int t = threadIdx.x;
    int c = (t < RG) ? regionBase[t] : 0;
    sh[t] = c;
    __syncthreads();
    for (int d = 1; d < 256; d <<= 1) {
        int v = (t >= d) ? sh[t - d] : 0;
        __syncthreads();
        sh[t] += v;
        __syncthreads();
    }
    if (t < RG) regionBase[t] = sh[t] - c;   // exclusive
    if (t == 0) regionBase[RG] = E;
}

// partition: slice s scatters its edges into region-major epack order using
// LDS cursors seeded from hist+regionBase. Plain stores only.
// epack = (dlocal << 17) | src
static __global__ void gcn364_partition(const int* __restrict__ src,
                                        const int* __restrict__ dst,
                                        const int* __restrict__ hist,
                                        const int* __restrict__ regionBase,
                                        int* __restrict__ epack,
                                        int E, int RG) {
    __shared__ int cur[256];
    int s = blockIdx.x;
    if (threadIdx.x < RG)
        cur[threadIdx.x] = hist[s * RG + threadIdx.x] + regionBase[threadIdx.x];
    __syncthreads();
    int elo = s * ECH;
    int ehi = elo + ECH; if (ehi > E) ehi = E;
    #pragma unroll 4
    for (int e = elo + threadIdx.x; e < ehi; e += 256) {
        int d = dst[e];
        int sv = src[e];
        int p = atomicAdd(&cur[d >> RGSH], 1);
        epack[p] = ((d & (RGSIZE - 1)) << 17) | sv;
    }
}

// build: one block per region. LDS deg hist over the region's contiguous
// epack run -> LDS scan -> absolute off[] (inclusive ends) -> LDS-cursor
// esrc placement (overwrites the dead hist). Also dinvs + xf4 scaling.
static __global__ void gcn364_build(const int* __restrict__ epack,
                                    const int* __restrict__ regionBase,
                                    int* __restrict__ off,
                                    int* __restrict__ esrc,
                                    float4* __restrict__ xf4,
                                    int N) {
    __shared__ int sdeg[RGSIZE];
    __shared__ int stmp[256];
    int r = blockIdx.x;
    int nlo = r << RGSH;
    int nn = N - nlo; if (nn > RGSIZE) nn = RGSIZE;
    int e0 = regionBase[r];
    int e1 = regionBase[r + 1];
    int t = threadIdx.x;

    sdeg[t] = 0; sdeg[t + 256] = 0;
    __syncthreads();
    #pragma unroll 4
    for (int p = e0 + t; p < e1; p += 256)
        atomicAdd(&sdeg[epack[p] >> 17], 1);
    __syncthreads();

    int a0 = sdeg[2 * t];
    int a1 = sdeg[2 * t + 1];
    int psum = a0 + a1;
    stmp[t] = psum;
    __syncthreads();
    for (int d = 1; d < 256; d <<= 1) {
        int val = (t >= d) ? stmp[t - d] : 0;
        __syncthreads();
        stmp[t] += val;
        __syncthreads();
    }
    int excl = stmp[t] - psum;

    if (2 * t < nn)     off[nlo + 2 * t]     = e0 + excl + a0;
    if (2 * t + 1 < nn) off[nlo + 2 * t + 1] = e0 + excl + a0 + a1;
    if (2 * t < nn) {
        float di = rsqrtf((float)a0 + 1.0f);
        float4 xv = xf4[nlo + 2 * t];
        xv.x *= di; xv.y *= di; xv.z *= di; xv.w = di;
        xf4[nlo + 2 * t] = xv;
    }
    if (2 * t + 1 < nn) {
        float di = rsqrtf((float)a1 + 1.0f);
        float4 xv = xf4[nlo + 2 * t + 1];
        xv.x *= di; xv.y *= di; xv.z *= di; xv.w = di;
        xf4[nlo + 2 * t + 1] = xv;
    }
    sdeg[2 * t]     = e0 + excl;
    sdeg[2 * t + 1] = e0 + excl + a0;
    __syncthreads();
    #pragma unroll 4
    for (int p = e0 + t; p < e1; p += 256) {
        int v = epack[p];
        int q = atomicAdd(&sdeg[v >> 17], 1);
        esrc[q] = v & 0x1FFFF;
    }
}

// Layer-1 aggregation -> u4 records. 16 lanes per node, 4 nodes per wave.
static __global__ void gcn364_aggu(const int* __restrict__ esrc,
                                   const int* __restrict__ off,
                                   const float4* __restrict__ xf4,
                                   float4* __restrict__ u4, int N) {
    int lane = threadIdx.x & 63;
    int wv = threadIdx.x >> 6;
    int grp = lane >> 4;
    int sub = lane & 15;
    int i = (blockIdx.x * 4 + wv) * 4 + grp;

    float a0 = 0.f, a1 = 0.f, a2 = 0.f;
    if (i < N) {
        int p0 = (i == 0) ? 0 : off[i - 1];
        int p1 = off[i];
        for (int p = p0 + sub; p < p1; p += 16) {
            float4 sv = xf4[esrc[p]];
            a0 += sv.x; a1 += sv.y; a2 += sv.z;
        }
    }
    for (int d = 1; d < 16; d <<= 1) {
        a0 += __shfl_xor(a0, d);
        a1 += __shfl_xor(a1, d);
        a2 += __shfl_xor(a2, d);
    }
    if (i < N && sub == 0) {
        float4 xi = xf4[i];
        float di = xi.w;
        u4[i] = make_float4(di * (a0 + xi.x), di * (a1 + xi.y), di * (a2 + xi.z), di);
    }
}

// per-edge layer-1 row recompute + accumulate (packed dual-fp32)
__device__ __forceinline__ void gcn364_edge(const float4 u,
                                            const gcn364_f2* wa2, const gcn364_f2* wb2,
                                            const gcn364_f2* wc2, const gcn364_f2* bb2,
                                            gcn364_f2* acc) {
    gcn364_f2 ux = {u.x, u.x}, uy = {u.y, u.y}, uz = {u.z, u.z}, uw = {u.w, u.w};
    gcn364_f2 zero = {0.f, 0.f};
    #pragma unroll
    for (int q = 0; q < 4; q++) {
        gcn364_f2 t = ux * wa2[q] + uy * wb2[q] + uz * wc2[q] + bb2[q];
        t = __builtin_elementwise_max(t, zero);
        acc[q] += uw * t;
    }
}

// Fused layer-2: phase A = block-cooperative bulk gather (R25) + per-edge
// layer-1 recompute; V tile -> bf16 LDS in MFMA A-frag layout. Phase B =
// MFMA 16x16x32 bf16 GEMM + relu, then block-level pool reduction (R26):
// per (wave,tt) lanes split their 4 rows into g==g0 / g!=g0 sums, shfl_xor
// (16/32) reduces across quads, quad0 stores spool[2][128]; barrier; <=256
// global atomics per block (zeros skipped).
#define MPB 16
static __global__ __launch_bounds__(256, 8) void gcn364_agg2pool(
        const int* __restrict__ esrc, const int* __restrict__ off,
        const float4* __restrict__ u4,
        const float* __restrict__ w1f, const float* __restrict__ b1f,
        const unsigned short* __restrict__ w2frag, const float* __restrict__ b2f,
        const int* __restrict__ batch, float* __restrict__ pooled, int N) {
    __shared__ unsigned short vshb[MPB][H + 8];   // bf16 V tile, A-frag friendly
    __shared__ float4 sstage[CHE];                // bulk-gathered u4 records
    __shared__ int soff[MPB + 1];                 // node edge-range ends
    __shared__ float spool[2][H];                 // per-block pool partials
    int i0 = blockIdx.x * MPB;
    int tid = threadIdx.x;
    int wave = tid >> 6;
    int lane = tid & 63;
    int grp = lane >> 4;
    int sub = lane & 15;
    int node = wave * 4 + grp;
    int i = i0 + node;

    if (tid <= MPB) {
        int idx = i0 - 1 + tid;
        int cidx = idx < N - 1 ? idx : N - 1;
        soff[tid] = (idx < 0) ? 0 : off[cidx];
    }

    gcn364_f2 wa2[4], wb2[4], wc2[4], bb2[4];
    #pragma unroll
    for (int q = 0; q < 4; q++) {
        int f = sub * 8 + q * 2;
        wa2[q] = (gcn364_f2){w1f[f], w1f[f + 1]};
        wb2[q] = (gcn364_f2){w1f[H + f], w1f[H + f + 1]};
        wc2[q] = (gcn364_f2){w1f[2 * H + f], w1f[2 * H + f + 1]};
        bb2[q] = (gcn364_f2){b1f[f], b1f[f + 1]};
    }
    __syncthreads();

    int s  = soff[node];      // this node's edge range [s, e)
    int e  = soff[node + 1];
    int e0 = soff[0];         // block edge range [e0, e1)
    int e1 = soff[MPB];

    gcn364_f2 acc[4];
    acc[0] = acc[1] = acc[2] = acc[3] = (gcn364_f2){0.f, 0.f};
    for (int cb = e0; cb < e1; cb += CHE) {
        int ce = cb + CHE; if (ce > e1) ce = e1;
        // bulk gather: 256 threads, coalesced esrc, scattered u4 16B reads,
        // linear LDS writes; no masking waste, full MLP.
        for (int p = cb + tid; p < ce; p += 256)
            sstage[p - cb] = u4[esrc[p]];
        __syncthreads();
        // consume: group-uniform slice, same-address b128 broadcast reads.
        int lo = s > cb ? s : cb;
        int hi = e < ce ? e : ce;
        #pragma unroll 4
        for (int p = lo; p < hi; p++) {
            float4 u = sstage[p - cb];
            gcn364_edge(u, wa2, wb2, wc2, bb2, acc);
        }
        __syncthreads();
    }
    float di = 0.f;
    if (i < N) {
        float4 uS = u4[i];   // self-loop record
        gcn364_edge(uS, wa2, wb2, wc2, bb2, acc);
        di = uS.w;
    }
    {   // V row -> bf16 LDS (feats sub*8..sub*8+7)
        gcn364_s8 o;
        o[0] = (short)gcn364_f2bf(acc[0].x * di);
        o[1] = (short)gcn364_f2bf(acc[0].y * di);
        o[2] = (short)gcn364_f2bf(acc[1].x * di);
        o[3] = (short)gcn364_f2bf(acc[1].y * di);
        o[4] = (short)gcn364_f2bf(acc[2].x * di);
        o[5] = (short)gcn364_f2bf(acc[2].y * di);
        o[6] = (short)gcn364_f2bf(acc[3].x * di);
        o[7] = (short)gcn364_f2bf(acc[3].y * di);
        *(gcn364_s8*)&vshb[node][sub * 8] = o;
    }
    __syncthreads();

    // Phase B: MFMA. A[m][k]: m = lane&15 (node), k = quad*8+j over chunks.
    int m = lane & 15;
    int quad = lane >> 4;
    int g0 = batch[i0];       // block's first graph (block spans <= 2)
    gcn364_s8 af[4];
    #pragma unroll
    for (int c = 0; c < 4; c++)
        af[c] = *(const gcn364_s8*)&vshb[m][c * 32 + quad * 8];

    #pragma unroll
    for (int tt = 0; tt < 2; tt++) {
        int t = wave * 2 + tt;                // n-tile 0..7
        gcn364_f4 cacc = {0.f, 0.f, 0.f, 0.f};
        #pragma unroll
        for (int c = 0; c < 4; c++) {
            gcn364_s8 bf8 = *(const gcn364_s8*)&w2frag[(((t * 4 + c) * 64) + lane) * 8];
            cacc = __builtin_amdgcn_mfma_f32_16x16x32_bf16(af[c], bf8, cacc, 0, 0, 0);
        }
        // C/D: col = lane&15 (feat within tile), row = (lane>>4)*4 + reg (node)
        int feat = t * 16 + m;
        float bb = b2f[feat];
        int baseRow = quad * 4;
        float sum0 = 0.0f, sum1 = 0.0f;   // g==g0 / g!=g0 partial sums
        #pragma unroll
        for (int r = 0; r < 4; r++) {
            int ii = i0 + baseRow + r;
            if (ii >= N) continue;
            float val = fmaxf(cacc[r] + bb, 0.0f);
            if (batch[ii] == g0) sum0 += val; else sum1 += val;
        }
        // reduce across the 4 quads (same feat, different nodes)
        sum0 += __shfl_xor(sum0, 16); sum0 += __shfl_xor(sum0, 32);
        sum1 += __shfl_xor(sum1, 16); sum1 += __shfl_xor(sum1, 32);
        if (quad == 0) {                   // single writer per (slot,feat)
            spool[0][feat] = sum0;
            spool[1][feat] = sum1;
        }
    }
    __syncthreads();
    // dump: <=256 global atomics per block, zeros skipped.
    {
        int slot = tid >> 7;
        int f = tid & (H - 1);
        float v = spool[slot][f];
        if (v != 0.0f) {
            int il = i0 + MPB - 1; if (il > N - 1) il = N - 1;
            int g = slot ? batch[il] : g0;
            atomicAdd(&pooled[g * H + f], v);
        }
    }
}

// out[g] = (pooled[g]/cnt_g) @ Wl + bl  -> detected dtype.
static __global__ void gcn364_final(const float* __restrict__ pooled,
                                    const int* __restrict__ batch,
                                    const float* __restrict__ wlf,
                                    const float* __restrict__ blf,
                                    const int* __restrict__ flag,
                                    void* __restrict__ out, int N, int G) {
    int g = blockIdx.x;
    int o = threadIdx.x;
    if (g >= G || o >= OUTF) return;
    int lo = 0, hi = N;
    while (lo < hi) { int m = (lo + hi) >> 1; if (batch[m] < g) lo = m + 1; else hi = m; }
    int a = lo;
    lo = 0; hi = N;
    while (lo < hi) { int m = (lo + hi) >> 1; if (batch[m] < g + 1) lo = m + 1; else hi = m; }
    float cn = (float)(lo - a);
    float inv = 1.0f / fmaxf(cn, 1.0f);
    float acc = 0.0f;
    for (int k = 0; k < H; k++)
        acc += pooled[g * H + k] * wlf[k * OUTF + o];
    float v = acc * inv + blf[o];
    if (*flag) ((float*)out)[g * OUTF + o] = v;
    else       ((unsigned short*)out)[g * OUTF + o] = gcn364_f2bf(v);
}

extern "C" void kernel_launch(void* const* d_in, const int* in_sizes, int n_in,
                              void* d_out, int out_size, void* d_ws, size_t ws_size,
                              hipStream_t stream) {
    const void* x  = d_in[0];
    const int* edge_index = (const int*)d_in[1];
    const int* batch      = (const int*)d_in[2];
    const void* W1 = d_in[3];
    const void* b1 = d_in[4];
    const void* W2 = d_in[5];
    const void* b2 = d_in[6];
    const void* Wl = d_in[7];
    const void* bl = d_in[8];

    const int N = in_sizes[0] / DIN;
    const int E = in_sizes[1] / 2;
    const int G = out_size / OUTF;
    const int* src = edge_index;
    const int* dst = edge_index + E;
    const int SH = (E + 8191) / 8192;         // legacy slice count: layout only
    const int S  = (E + ECH - 1) / ECH;       // edge slices (782)
    const int RG = (N + RGSIZE - 1) >> RGSH;  // node regions (<= 256)
    const int GH = G * H;

    // ---- workspace layout: byte-identical offsets to the verified R19
    // layout (legacy hist slot reserved/unused); the real hist (S*RG ints,
    // 613KB) ALIASES the esrc slot -- dead before build writes esrc. ----
    char* wsb = (char*)d_ws;
    float* pooled     = (float*)wsb;                              // G*H
    int*   histLeg    = (int*)(pooled + (size_t)GH);              // legacy slot
    int*   regionBase = histLeg + (size_t)SH * RG;                // RG+1
    int*   off        = regionBase + RG + 1;                      // N
    int*   flag       = off + N;                                  // 1
    size_t ofs = (((size_t)((char*)(flag + 1) - wsb)) + 15) & ~(size_t)15;
    float4* xf4  = (float4*)(wsb + ofs);                          // N float4
    float4* u4   = xf4 + N;                                       // N float4
    float*  wf   = (float*)(u4 + N);                              // NWEIGHT
    size_t ofs2 = (((size_t)((char*)(wf + NWEIGHT) - wsb)) + 15) & ~(size_t)15;
    unsigned short* w2frag = (unsigned short*)(wsb + ofs2);       // 16384 ushort
    int*    epack = (int*)(w2frag + W2FRAG_N);                    // E
    int*    esrc  = epack + E;                                    // E
    int*    hist  = esrc;   // alias: hist dead before build writes esrc

    float* w1f = wf;
    float* b1f = w1f + 384;
    float* b2f = b1f + 128 + 16384;
    float* wlf = b2f + 128;
    float* blf = wlf + 1280;

    {
        int convBlocks = (N + NWEIGHT + 255) / 256;
        int gmax = (S > convBlocks) ? S : convBlocks;
        gcn364_histconv<<<gmax, 256, 0, stream>>>(
            x, W1, b1, W2, b2, Wl, bl, flag, xf4, wf, w2frag, pooled,
            dst, hist, N, E, S, RG, GH);
    }
    gcn364_scanHpar<<<RG, 256, 0, stream>>>(hist, regionBase, S, RG);
    gcn364_scanR<<<1, 256, 0, stream>>>(regionBase, RG, E);
    gcn364_partition<<<S, 256, 0, stream>>>(src, dst, hist, regionBase, epack, E, RG);
    gcn364_build<<<RG, 256, 0, stream>>>(epack, regionBase, off, esrc, xf4, N);
    gcn364_aggu<<<(N + 15) / 16, 256, 0, stream>>>(esrc, off, xf4, u4, N);
    gcn364_agg2pool<<<(N + MPB - 1) / MPB, 256, 0, stream>>>(
        esrc, off, u4, w1f, b1f, w2frag, b2f, batch, pooled, N);
    gcn364_final<<<G, 64, 0, stream>>>(pooled, batch, wlf, blf, flag, d_out, N, G);
}

// Round 9
// 186.549 us; speedup vs baseline: 1.3083x; 1.0360x over previous
//
#include <hip/hip_runtime.h>

// GCN: 2x GCNConv(+self-loop sym-norm) + ReLU, global mean pool, linear head.
// N=100000, E=1600000, G=100, D_IN=3, H=128, OUT=10.
//
// R27->R28: thread-count on the two 196-block kernels (the only ones every
// occupancy fix skipped). ECH=2048 was neutral -> partition/histconv were
// not the cost; the ~95us of unexplained pipeline time must be latency
// exposure in build (196 blk x 256 thr: 0.77 blocks/CU AND 4 waves/block
// for dependent epack loads + LDS atomics + 16-barrier scan + scatter) and
// scanHpar (196 blk, 4 serial chunks x 16 barriers, stride-784B loads).
//  * build: 256 -> 1024 threads. Edge loops stride blockDim (4x MLP);
//    scan/off/xf4 phases guarded to t<256 with barriers unconditional.
//  * scanHpar: 256 -> 1024 threads; S=782 fits ONE chunk -> single 10-step
//    ladder (20 barriers vs 64), all strided loads in flight at once.
// Everything else R27-exact (bulk-gather agg2pool, block-pool reduction,
// hist-aliases-esrc layout).
//
// All kernels static + gcn364_ prefix (cross-.so symbol collisions caused the
// round-1 silent failure). Runtime dtype probe handles bf16/fp32 harness mode.

#define DIN 3
#define H 128
#define OUTF 10
#define NWEIGHT (384 + 128 + 16384 + 128 + 1280 + 10)  // W1,b1,W2,b2,Wl,bl
#define ECH 2048            // edges per slice (hist aliases esrc slot)
#define RGSH 9              // region = 512 nodes
#define RGSIZE 512
#define W2FRAG_N 16384      // 8 tiles * 4 kchunks * 64 lanes * 8 elems
#define CHE 512             // bulk-gather stage records (float4)

typedef float gcn364_f2 __attribute__((ext_vector_type(2)));
typedef float gcn364_f4 __attribute__((ext_vector_type(4)));
typedef short gcn364_s8 __attribute__((ext_vector_type(8)));

__device__ __forceinline__ float gcn364_bf2f(unsigned short u) {
    return __uint_as_float(((unsigned int)u) << 16);
}
__device__ __forceinline__ unsigned short gcn364_f2bf(float f) {
    unsigned int u = __float_as_uint(f);
    u += 0x7FFFu + ((u >> 16) & 1u);   // round-to-nearest-even
    return (unsigned short)(u >> 16);
}

// per-wave dtype probe over x's first 256 ushorts: 1 -> fp32, 0 -> bf16.
__device__ __forceinline__ int gcn364_probe(const unsigned short* __restrict__ xs16) {
    int lane = threadIdx.x & 63;
    int outl = 0;
    #pragma unroll
    for (int k = 0; k < 4; k++) {
        unsigned short u = xs16[lane * 4 + k];
        int e = (u >> 7) & 0xFF;
        outl += (e < 100 || e > 140) ? 1 : 0;
    }
    #pragma unroll
    for (int d = 1; d < 64; d <<= 1) outl += __shfl_xor(outl, d);
    return (outl > 32) ? 1 : 0;
}

// histconv: blocks < S build the per-slice region histogram (coalesced
// hist[s*RG + r] store); blocks < convBlocks also convert x -> xf4 /
// weights -> wf, build the W2 B-fragment table (bf16), zero pooled, publish
// flag. hist lives in the (currently dead) esrc slot.
static __global__ void gcn364_histconv(const void* __restrict__ x,
                                       const void* __restrict__ W1, const void* __restrict__ b1,
                                       const void* __restrict__ W2, const void* __restrict__ b2,
                                       const void* __restrict__ Wl, const void* __restrict__ bl,
                                       int* __restrict__ flag,
                                       float4* __restrict__ xf4, float* __restrict__ wf,
                                       unsigned short* __restrict__ w2frag,
                                       float* __restrict__ pooled,
                                       const int* __restrict__ edst,
                                       int* __restrict__ hist,
                                       int N, int E, int S, int RG, int GH) {
    __shared__ int h[256];
    if (blockIdx.x < (unsigned)S) {
        h[threadIdx.x] = 0;
        __syncthreads();
        int elo = blockIdx.x * ECH;
        int ehi = elo + ECH; if (ehi > E) ehi = E;
        #pragma unroll 4
        for (int e = elo + threadIdx.x; e < ehi; e += 256)
            atomicAdd(&h[edst[e] >> RGSH], 1);
        __syncthreads();
        if (threadIdx.x < RG) hist[blockIdx.x * RG + threadIdx.x] = h[threadIdx.x];
    }
    int i = blockIdx.x * blockDim.x + threadIdx.x;
    if (i < GH) pooled[i] = 0.0f;
    int total = N + NWEIGHT;
    if ((int)blockIdx.x * 256 < total) {
        int fl = gcn364_probe((const unsigned short*)x);
        if (i == 0) *flag = fl;
        if (i < N) {
            float a, b, c;
            if (fl) {
                const float* xs = (const float*)x;
                a = xs[3 * i]; b = xs[3 * i + 1]; c = xs[3 * i + 2];
            } else {
                const unsigned short* xs = (const unsigned short*)x;
                a = gcn364_bf2f(xs[3 * i]);
                b = gcn364_bf2f(xs[3 * i + 1]);
                c = gcn364_bf2f(xs[3 * i + 2]);
            }
            xf4[i] = make_float4(a, b, c, 0.f);
        } else if (i < total) {
            int j = i - N;
            const void* srcp;
            if      (j < 384)                       { srcp = W1; }
            else if ((j -= 384)   < 128)            { srcp = b1; }
            else if ((j -= 128)   < 16384)          { srcp = W2; }
            else if ((j -= 16384) < 128)            { srcp = b2; }
            else if ((j -= 128)   < 1280)           { srcp = Wl; }
            else    { j -= 1280;                      srcp = bl; }
            wf[i - N] = fl ? ((const float*)srcp)[j]
                           : gcn364_bf2f(((const unsigned short*)srcp)[j]);
        }
        // W2 B-fragment table: frag[t][c][lane][j] = bf16(W2[k][n]),
        // k = c*32 + (lane>>4)*8 + j, n = t*16 + (lane&15)
        if (i < W2FRAG_N) {
            int fl2 = fl;
            int j = i & 7;
            int l = (i >> 3) & 63;
            int c = (i >> 9) & 3;
            int t = i >> 11;
            int k = c * 32 + (l >> 4) * 8 + j;
            int n = t * 16 + (l & 15);
            float w = fl2 ? ((const float*)W2)[k * H + n]
                          : gcn364_bf2f(((const unsigned short*)W2)[k * H + n]);
            w2frag[i] = gcn364_f2bf(w);
        }
    }
}

// scanHpar (1024 thr): block r turns hist[s*RG+r] (counts) into the
// exclusive prefix over slices s, in place; region-r total -> regionBase[r].
// S=782 fits one 1024-wide chunk: single 10-step ladder.
static __global__ void gcn364_scanHpar(int* __restrict__ hist,
                                       int* __restrict__ regionBase,
                                       int S, int RG) {
    __shared__ int sh[1024];
    int r = blockIdx.x;
    int t = threadIdx.x;
    int carry = 0;
    for (int s0 = 0; s0 < S; s0 += 1024) {
        int s = s0 + t;
        int c = (s < S) ? hist[s * RG + r] : 0;
        sh[t] = c;
        __syncthreads();
        for (int d = 1; d < 1024; d <<= 1) {
            int v = (t >= d) ? sh[t - d] : 0;
            __syncthreads();
            sh[t] += v;
            __syncthreads();
        }
        if (s < S) hist[s * RG + r] = carry + sh[t] - c;   // exclusive prefix
        int tot = sh[1023];
        __syncthreads();   // everyone reads sh[1023] before next chunk
        carry += tot;
    }
    if (t == 0) regionBase[r] = carry;   // region total (scanned by scanR)
}

// scanR (1 block): IN-PLACE exclusive scan of regionBase (region totals ->
// exclusive bases); regionBase[RG] = E. Requires RG <= 256 (RG=196 here).
static __global__ void gcn364_scanR(int* __restrict__ regionBase,
                                    int RG, int E) {
    __shared__ int sh[256];
    int t = threadIdx.x;
    int c = (t < RG) ? regionBase[t] : 0;
    sh[t] = c;
    __syncthreads();
    for (int d = 1; d < 256; d <<= 1) {
        int v = (t >= d) ? sh[t - d] : 0;
        __syncthreads();
        sh[t] += v;
        __syncthreads();
    }
    if (t < RG) regionBase[t] = sh[t] - c;   // exclusive
    if (t == 0) regionBase[RG] = E;
}

// partition: slice s scatters its edges into region-major epack order using
// LDS cursors seeded from hist+regionBase. Plain stores only.
// epack = (dlocal << 17) | src
static __global__ void gcn364_partition(const int* __restrict__ src,
                                        const int* __restrict__ dst,
                                        const int* __restrict__ hist,
                                        const int* __restrict__ regionBase,
                                        int* __restrict__ epack,
                                        int E, int RG) {
    __shared__ int cur[256];
    int s = blockIdx.x;
    if (threadIdx.x < RG)
        cur[threadIdx.x] = hist[s * RG + threadIdx.x] + regionBase[threadIdx.x];
    __syncthreads();
    int elo = s * ECH;
    int ehi = elo + ECH; if (ehi > E) ehi = E;
    #pragma unroll 4
    for (int e = elo + threadIdx.x; e < ehi; e += 256) {
        int d = dst[e];
        int sv = src[e];
        int p = atomicAdd(&cur[d >> RGSH], 1);
        epack[p] = ((d & (RGSIZE - 1)) << 17) | sv;
    }
}

// build (1024 thr): one block per region. LDS deg hist over the region's
// contiguous epack run -> LDS scan (t<256, barriers unconditional) ->
// absolute off[] -> LDS-cursor esrc placement. Also dinvs + xf4 scaling.
static __global__ void gcn364_build(const int* __restrict__ epack,
                                    const int* __restrict__ regionBase,
                                    int* __restrict__ off,
                                    int* __restrict__ esrc,
                                    float4* __restrict__ xf4,
                                    int N) {
    __shared__ int sdeg[RGSIZE];
    __shared__ int stmp[256];
    int r = blockIdx.x;
    int nlo = r << RGSH;
    int nn = N - nlo; if (nn > RGSIZE) nn = RGSIZE;
    int e0 = regionBase[r];
    int e1 = regionBase[r + 1];
    int t = threadIdx.x;
    int bdim = blockDim.x;

    if (t < RGSIZE) sdeg[t] = 0;
    __syncthreads();
    #pragma unroll 4
    for (int p = e0 + t; p < e1; p += bdim)
        atomicAdd(&sdeg[epack[p] >> 17], 1);
    __syncthreads();

    int a0 = 0, a1 = 0, psum = 0;
    if (t < 256) {
        a0 = sdeg[2 * t];
        a1 = sdeg[2 * t + 1];
        psum = a0 + a1;
        stmp[t] = psum;
    }
    __syncthreads();
    for (int d = 1; d < 256; d <<= 1) {
        int val = (t >= d && t < 256) ? stmp[t - d] : 0;
        __syncthreads();
        if (t < 256) stmp[t] += val;
        __syncthreads();
    }
    if (t < 256) {
        int excl = stmp[t] - psum;

        if (2 * t < nn)     off[nlo + 2 * t]     = e0 + excl + a0;
        if (2 * t + 1 < nn) off[nlo + 2 * t + 1] = e0 + excl + a0 + a1;
        if (2 * t < nn) {
            float di = rsqrtf((float)a0 + 1.0f);
            float4 xv = xf4[nlo + 2 * t];
            xv.x *= di; xv.y *= di; xv.z *= di; xv.w = di;
            xf4[nlo + 2 * t] = xv;
        }
        if (2 * t + 1 < nn) {
            float di = rsqrtf((float)a1 + 1.0f);
            float4 xv = xf4[nlo + 2 * t + 1];
            xv.x *= di; xv.y *= di; xv.z *= di; xv.w = di;
            xf4[nlo + 2 * t + 1] = xv;
        }
        sdeg[2 * t]     = e0 + excl;
        sdeg[2 * t + 1] = e0 + excl + a0;
    }
    __syncthreads();
    #pragma unroll 4
    for (int p = e0 + t; p < e1; p += bdim) {
        int v = epack[p];
        int q = atomicAdd(&sdeg[v >> 17], 1);
        esrc[q] = v & 0x1FFFF;
    }
}

// Layer-1 aggregation -> u4 records. 16 lanes per node, 4 nodes per wave.
static __global__ void gcn364_aggu(const int* __restrict__ esrc,
                                   const int* __restrict__ off,
                                   const float4* __restrict__ xf4,
                                   float4* __restrict__ u4, int N) {
    int lane = threadIdx.x & 63;
    int wv = threadIdx.x >> 6;
    int grp = lane >> 4;
    int sub = lane & 15;
    int i = (blockIdx.x * 4 + wv) * 4 + grp;

    float a0 = 0.f, a1 = 0.f, a2 = 0.f;
    if (i < N) {
        int p0 = (i == 0) ? 0 : off[i - 1];
        int p1 = off[i];
        for (int p = p0 + sub; p < p1; p += 16) {
            float4 sv = xf4[esrc[p]];
            a0 += sv.x; a1 += sv.y; a2 += sv.z;
        }
    }
    for (int d = 1; d < 16; d <<= 1) {
        a0 += __shfl_xor(a0, d);
        a1 += __shfl_xor(a1, d);
        a2 += __shfl_xor(a2, d);
    }
    if (i < N && sub == 0) {
        float4 xi = xf4[i];
        float di = xi.w;
        u4[i] = make_float4(di * (a0 + xi.x), di * (a1 + xi.y), di * (a2 + xi.z), di);
    }
}

// per-edge layer-1 row recompute + accumulate (packed dual-fp32)
__device__ __forceinline__ void gcn364_edge(const float4 u,
                                            const gcn364_f2* wa2, const gcn364_f2* wb2,
                                            const gcn364_f2* wc2, const gcn364_f2* bb2,
                                            gcn364_f2* acc) {
    gcn364_f2 ux = {u.x, u.x}, uy = {u.y, u.y}, uz = {u.z, u.z}, uw = {u.w, u.w};
    gcn364_f2 zero = {0.f, 0.f};
    #pragma unroll
    for (int q = 0; q < 4; q++) {
        gcn364_f2 t = ux * wa2[q] + uy * wb2[q] + uz * wc2[q] + bb2[q];
        t = __builtin_elementwise_max(t, zero);
        acc[q] += uw * t;
    }
}

// Fused layer-2: phase A = block-cooperative bulk gather (R25) + per-edge
// layer-1 recompute; V tile -> bf16 LDS in MFMA A-frag layout. Phase B =
// MFMA 16x16x32 bf16 GEMM + relu, then block-level pool reduction (R26):
// per (wave,tt) lanes split their 4 rows into g==g0 / g!=g0 sums, shfl_xor
// (16/32) reduces across quads, quad0 stores spool[2][128]; barrier; <=256
// global atomics per block (zeros skipped).
#define MPB 16
static __global__ __launch_bounds__(256, 8) void gcn364_agg2pool(
        const int* __restrict__ esrc, const int* __restrict__ off,
        const float4* __restrict__ u4,
        const float* __restrict__ w1f, const float* __restrict__ b1f,
        const unsigned short* __restrict__ w2frag, const float* __restrict__ b2f,
        const int* __restrict__ batch, float* __restrict__ pooled, int N) {
    __shared__ unsigned short vshb[MPB][H + 8];   // bf16 V tile, A-frag friendly
    __shared__ float4 sstage[CHE];                // bulk-gathered u4 records
    __shared__ int soff[MPB + 1];                 // node edge-range ends
    __shared__ float spool[2][H];                 // per-block pool partials
    int i0 = blockIdx.x * MPB;
    int tid = threadIdx.x;
    int wave = tid >> 6;
    int lane = tid & 63;
    int grp = lane >> 4;
    int sub = lane & 15;
    int node = wave * 4 + grp;
    int i = i0 + node;

    if (tid <= MPB) {
        int idx = i0 - 1 + tid;
        int cidx = idx < N - 1 ? idx : N - 1;
        soff[tid] = (idx < 0) ? 0 : off[cidx];
    }

    gcn364_f2 wa2[4], wb2[4], wc2[4], bb2[4];
    #pragma unroll
    for (int q = 0; q < 4; q++) {
        int f = sub * 8 + q * 2;
        wa2[q] = (gcn364_f2){w1f[f], w1f[f + 1]};
        wb2[q] = (gcn364_f2){w1f[H + f], w1f[H + f + 1]};
        wc2[q] = (gcn364_f2){w1f[2 * H + f], w1f[2 * H + f + 1]};
        bb2[q] = (gcn364_f2){b1f[f], b1f[f + 1]};
    }
    __syncthreads();

    int s  = soff[node];      // this node's edge range [s, e)
    int e  = soff[node + 1];
    int e0 = soff[0];         // block edge range [e0, e1)
    int e1 = soff[MPB];

    gcn364_f2 acc[4];
    acc[0] = acc[1] = acc[2] = acc[3] = (gcn364_f2){0.f, 0.f};
    for (int cb = e0; cb < e1; cb += CHE) {
        int ce = cb + CHE; if (ce > e1) ce = e1;
        // bulk gather: 256 threads, coalesced esrc, scattered u4 16B reads,
        // linear LDS writes; no masking waste, full MLP.
        for (int p = cb + tid; p < ce; p += 256)
            sstage[p - cb] = u4[esrc[p]];
        __syncthreads();
        // consume: group-uniform slice, same-address b128 broadcast reads.
        int lo = s > cb ? s : cb;
        int hi = e < ce ? e : ce;
        #pragma unroll 4
        for (int p = lo; p < hi; p++) {
            float4 u = sstage[p - cb];
            gcn364_edge(u, wa2, wb2, wc2, bb2, acc);
        }
        __syncthreads();
    }
    float di = 0.f;
    if (i < N) {
        float4 uS = u4[i];   // self-loop record
        gcn364_edge(uS, wa2, wb2, wc2, bb2, acc);
        di = uS.w;
    }
    {   // V row -> bf16 LDS (feats sub*8..sub*8+7)
        gcn364_s8 o;
        o[0] = (short)gcn364_f2bf(acc[0].x * di);
        o[1] = (short)gcn364_f2bf(acc[0].y * di);
        o[2] = (short)gcn364_f2bf(acc[1].x * di);
        o[3] = (short)gcn364_f2bf(acc[1].y * di);
        o[4] = (short)gcn364_f2bf(acc[2].x * di);
        o[5] = (short)gcn364_f2bf(acc[2].y * di);
        o[6] = (short)gcn364_f2bf(acc[3].x * di);
        o[7] = (short)gcn364_f2bf(acc[3].y * di);
        *(gcn364_s8*)&vshb[node][sub * 8] = o;
    }
    __syncthreads();

    // Phase B: MFMA. A[m][k]: m = lane&15 (node), k = quad*8+j over chunks.
    int m = lane & 15;
    int quad = lane >> 4;
    int g0 = batch[i0];       // block's first graph (block spans <= 2)
    gcn364_s8 af[4];
    #pragma unroll
    for (int c = 0; c < 4; c++)
        af[c] = *(const gcn364_s8*)&vshb[m][c * 32 + quad * 8];

    #pragma unroll
    for (int tt = 0; tt < 2; tt++) {
        int t = wave * 2 + tt;                // n-tile 0..7
        gcn364_f4 cacc = {0.f, 0.f, 0.f, 0.f};
        #pragma unroll
        for (int c = 0; c < 4; c++) {
            gcn364_s8 bf8 = *(const gcn364_s8*)&w2frag[(((t * 4 + c) * 64) + lane) * 8];
            cacc = __builtin_amdgcn_mfma_f32_16x16x32_bf16(af[c], bf8, cacc, 0, 0, 0);
        }
        // C/D: col = lane&15 (feat within tile), row = (lane>>4)*4 + reg (node)
        int feat = t * 16 + m;
        float bb = b2f[feat];
        int baseRow = quad * 4;
        float sum0 = 0.0f, sum1 = 0.0f;   // g==g0 / g!=g0 partial sums
        #pragma unroll
        for (int r = 0; r < 4; r++) {
            int ii = i0 + baseRow + r;
            if (ii >= N) continue;
            float val = fmaxf(cacc[r] + bb, 0.0f);
            if (batch[ii] == g0) sum0 += val; else sum1 += val;
        }
        // reduce across the 4 quads (same feat, different nodes)
        sum0 += __shfl_xor(sum0, 16); sum0 += __shfl_xor(sum0, 32);
        sum1 += __shfl_xor(sum1, 16); sum1 += __shfl_xor(sum1, 32);
        if (quad == 0) {                   // single writer per (slot,feat)
            spool[0][feat] = sum0;
            spool[1][feat] = sum1;
        }
    }
    __syncthreads();
    // dump: <=256 global atomics per block, zeros skipped.
    {
        int slot = tid >> 7;
        int f = tid & (H - 1);
        float v = spool[slot][f];
        if (v != 0.0f) {
            int il = i0 + MPB - 1; if (il > N - 1) il = N - 1;
            int g = slot ? batch[il] : g0;
            atomicAdd(&pooled[g * H + f], v);
        }
    }
}

// out[g] = (pooled[g]/cnt_g) @ Wl + bl  -> detected dtype.
static __global__ void gcn364_final(const float* __restrict__ pooled,
                                    const int* __restrict__ batch,
                                    const float* __restrict__ wlf,
                                    const float* __restrict__ blf,
                                    const int* __restrict__ flag,
                                    void* __restrict__ out, int N, int G) {
    int g = blockIdx.x;
    int o = threadIdx.x;
    if (g >= G || o >= OUTF) return;
    int lo = 0, hi = N;
    while (lo < hi) { int m = (lo + hi) >> 1; if (batch[m] < g) lo = m + 1; else hi = m; }
    int a = lo;
    lo = 0; hi = N;
    while (lo < hi) { int m = (lo + hi) >> 1; if (batch[m] < g + 1) lo = m + 1; else hi = m; }
    float cn = (float)(lo - a);
    float inv = 1.0f / fmaxf(cn, 1.0f);
    float acc = 0.0f;
    for (int k = 0; k < H; k++)
        acc += pooled[g * H + k] * wlf[k * OUTF + o];
    float v = acc * inv + blf[o];
    if (*flag) ((float*)out)[g * OUTF + o] = v;
    else       ((unsigned short*)out)[g * OUTF + o] = gcn364_f2bf(v);
}

extern "C" void kernel_launch(void* const* d_in, const int* in_sizes, int n_in,
                              void* d_out, int out_size, void* d_ws, size_t ws_size,
                              hipStream_t stream) {
    const void* x  = d_in[0];
    const int* edge_index = (const int*)d_in[1];
    const int* batch      = (const int*)d_in[2];
    const void* W1 = d_in[3];
    const void* b1 = d_in[4];
    const void* W2 = d_in[5];
    const void* b2 = d_in[6];
    const void* Wl = d_in[7];
    const void* bl = d_in[8];

    const int N = in_sizes[0] / DIN;
    const int E = in_sizes[1] / 2;
    const int G = out_size / OUTF;
    const int* src = edge_index;
    const int* dst = edge_index + E;
    const int SH = (E + 8191) / 8192;         // legacy slice count: layout only
    const int S  = (E + ECH - 1) / ECH;       // edge slices (782)
    const int RG = (N + RGSIZE - 1) >> RGSH;  // node regions (<= 256)
    const int GH = G * H;

    // ---- workspace layout: byte-identical offsets to the verified R19
    // layout (legacy hist slot reserved/unused); the real hist (S*RG ints,
    // 613KB) ALIASES the esrc slot -- dead before build writes esrc. ----
    char* wsb = (char*)d_ws;
    float* pooled     = (float*)wsb;                              // G*H
    int*   histLeg    = (int*)(pooled + (size_t)GH);              // legacy slot
    int*   regionBase = histLeg + (size_t)SH * RG;                // RG+1
    int*   off        = regionBase + RG + 1;                      // N
    int*   flag       = off + N;                                  // 1
    size_t ofs = (((size_t)((char*)(flag + 1) - wsb)) + 15) & ~(size_t)15;
    float4* xf4  = (float4*)(wsb + ofs);                          // N float4
    float4* u4   = xf4 + N;                                       // N float4
    float*  wf   = (float*)(u4 + N);                              // NWEIGHT
    size_t ofs2 = (((size_t)((char*)(wf + NWEIGHT) - wsb)) + 15) & ~(size_t)15;
    unsigned short* w2frag = (unsigned short*)(wsb + ofs2);       // 16384 ushort
    int*    epack = (int*)(w2frag + W2FRAG_N);                    // E
    int*    esrc  = epack + E;                                    // E
    int*    hist  = esrc;   // alias: hist dead before build writes esrc

    float* w1f = wf;
    float* b1f = w1f + 384;
    float* b2f = b1f + 128 + 16384;
    float* wlf = b2f + 128;
    float* blf = wlf + 1280;

    {
        int convBlocks = (N + NWEIGHT + 255) / 256;
        int gmax = (S > convBlocks) ? S : convBlocks;
        gcn364_histconv<<<gmax, 256, 0, stream>>>(
            x, W1, b1, W2, b2, Wl, bl, flag, xf4, wf, w2frag, pooled,
            dst, hist, N, E, S, RG, GH);
    }
    gcn364_scanHpar<<<RG, 1024, 0, stream>>>(hist, regionBase, S, RG);
    gcn364_scanR<<<1, 256, 0, stream>>>(regionBase, RG, E);
    gcn364_partition<<<S, 256, 0, stream>>>(src, dst, hist, regionBase, epack, E, RG);
    gcn364_build<<<RG, 1024, 0, stream>>>(epack, regionBase, off, esrc, xf4, N);
    gcn364_aggu<<<(N + 15) / 16, 256, 0, stream>>>(esrc, off, xf4, u4, N);
    gcn364_agg2pool<<<(N + MPB - 1) / MPB, 256, 0, stream>>>(
        esrc, off, u4, w1f, b1f, w2frag, b2f, batch, pooled, N);
    gcn364_final<<<G, 64, 0, stream>>>(pooled, batch, wlf, blf, flag, d_out, N, G);
}